// Round 4
// baseline (1558.982 us; speedup 1.0000x reference)
//
#include <hip/hip_runtime.h>
#include <cfloat>
#include <math.h>

constexpr int B_ = 8, N_ = 4096, S_ = 1024, NS_ = 32;
constexpr int R_ = B_ * S_ * NS_;          // 262144 rows (b,s,k)
constexpr float EPS_ = 1e-5f;

// ---------------------------------------------------------------- DPP helpers
// u64 max across wave: (hi,lo) pair, result valid in lane 63.
__device__ __forceinline__ void dpp_max_u64(unsigned& hi, unsigned& lo) {
#define STEP_(ctrl) { \
    unsigned h2 = (unsigned)__builtin_amdgcn_update_dpp((int)hi, (int)hi, ctrl, 0xf, 0xf, false); \
    unsigned l2 = (unsigned)__builtin_amdgcn_update_dpp((int)lo, (int)lo, ctrl, 0xf, 0xf, false); \
    if (h2 > hi || (h2 == hi && l2 > lo)) { hi = h2; lo = l2; } }
    STEP_(0x111) STEP_(0x112) STEP_(0x114) STEP_(0x118) STEP_(0x142) STEP_(0x143)
#undef STEP_
}
__device__ __forceinline__ void dpp_min_u64(unsigned& hi, unsigned& lo) {
#define STEP_(ctrl) { \
    unsigned h2 = (unsigned)__builtin_amdgcn_update_dpp((int)hi, (int)hi, ctrl, 0xf, 0xf, false); \
    unsigned l2 = (unsigned)__builtin_amdgcn_update_dpp((int)lo, (int)lo, ctrl, 0xf, 0xf, false); \
    if (h2 < hi || (h2 == hi && l2 < lo)) { hi = h2; lo = l2; } }
    STEP_(0x111) STEP_(0x112) STEP_(0x114) STEP_(0x118) STEP_(0x142) STEP_(0x143)
#undef STEP_
}
// f32 wave sum (canonical shr/bcast sequence), result valid in lane 63.
__device__ __forceinline__ float dpp_sum_f32(float x) {
#define ADD_(ctrl, rm) { \
    int t_ = __builtin_amdgcn_update_dpp(0, __float_as_int(x), ctrl, rm, 0xf, true); \
    x += __int_as_float(t_); }
    ADD_(0x111, 0xf) ADD_(0x112, 0xf) ADD_(0x114, 0xf) ADD_(0x118, 0xf)
    ADD_(0x142, 0xa) ADD_(0x143, 0xc)
#undef ADD_
    return x;
}

// ---------------------------------------------------------------- FPS
// One block per batch, 512 threads x 8 points. Exact reference semantics:
// ct_idx[0]=0; dist=min(dist,d); argmax with first-index tie-break.
// Single-phase reduce: u64 pack (dist_bits<<32)|~idx -> 7-deep register tree
// -> 6-stage DPP u64 max -> 8-entry LDS combine (parity, single barrier).
__global__ __launch_bounds__(512) void fps_kernel(const float* __restrict__ xyz,
                                                  int* __restrict__ ct_idx) {
    int b = blockIdx.x;
    const float* xb = xyz + (size_t)b * 3 * N_;
    int t = threadIdx.x;
    __shared__ float sx[N_], sy[N_], sz[N_];
    __shared__ unsigned long long sb[2][8];
    for (int i = t; i < N_; i += 512) {
        sx[i] = xb[i];
        sy[i] = xb[N_ + i];
        sz[i] = xb[2 * N_ + i];
    }
    float px[8], py[8], pz[8], dist[8];
    unsigned inv[8];
#pragma unroll
    for (int j = 0; j < 8; j++) {
        int n = j * 512 + t;
        px[j] = xb[n];
        py[j] = xb[N_ + n];
        pz[j] = xb[2 * N_ + n];
        dist[j] = 1e10f;
        inv[j] = ~(unsigned)n;
    }
    __syncthreads();
    float cx = sx[0], cy = sy[0], cz = sz[0];
    int far = 0;
    int w = t >> 6;
    for (int it = 0; it < S_; it++) {
        if (t == 0) ct_idx[b * S_ + it] = far;
        unsigned long long pk[8];
#pragma unroll
        for (int j = 0; j < 8; j++) {
            float dx = px[j] - cx, dy = py[j] - cy, dz = pz[j] - cz;
            float d = dx * dx;
            d = fmaf(dy, dy, d);
            d = fmaf(dz, dz, d);                  // same value chain as passing version
            dist[j] = fminf(dist[j], d);
            pk[j] = ((unsigned long long)__float_as_uint(dist[j]) << 32) | inv[j];
        }
        unsigned long long m4a = pk[0] > pk[1] ? pk[0] : pk[1];
        unsigned long long m4b = pk[2] > pk[3] ? pk[2] : pk[3];
        unsigned long long m4c = pk[4] > pk[5] ? pk[4] : pk[5];
        unsigned long long m4d = pk[6] > pk[7] ? pk[6] : pk[7];
        unsigned long long m2a = m4a > m4b ? m4a : m4b;
        unsigned long long m2b = m4c > m4d ? m4c : m4d;
        unsigned long long best = m2a > m2b ? m2a : m2b;
        unsigned hi = (unsigned)(best >> 32), lo = (unsigned)best;
        dpp_max_u64(hi, lo);
        int p = it & 1;
        if ((t & 63) == 63) sb[p][w] = ((unsigned long long)hi << 32) | lo;
        __syncthreads();
        unsigned long long b0 = sb[p][0], b1 = sb[p][1], b2 = sb[p][2], b3 = sb[p][3];
        unsigned long long b4 = sb[p][4], b5 = sb[p][5], b6 = sb[p][6], b7 = sb[p][7];
        unsigned long long ma = b0 > b1 ? b0 : b1;
        unsigned long long mb = b2 > b3 ? b2 : b3;
        unsigned long long mc = b4 > b5 ? b4 : b5;
        unsigned long long md = b6 > b7 ? b6 : b7;
        unsigned long long me = ma > mb ? ma : mb;
        unsigned long long mf = mc > md ? mc : md;
        unsigned long long bw = me > mf ? me : mf;
        far = (int)(~(unsigned)(bw & 0xffffffffu));
        cx = sx[far]; cy = sy[far]; cz = sz[far];
        // no trailing barrier: next iter writes the OTHER parity buffer; a wave
        // reaches iter+2's write only after all waves passed iter+1's barrier.
    }
}

// ---------------------------------------------------------------- kNN
// One block per (b,s). Order-preserving u32 keys precomputed once; per iter:
// u64 (key<<32)|idx min tree -> DPP u64 min -> 4-entry LDS combine (parity,
// single barrier). Tie -> smaller index (= lax.top_k selection set).
__global__ __launch_bounds__(256) void knn_kernel(const float* __restrict__ xyz,
                                                  const int* __restrict__ ct_idx,
                                                  int* __restrict__ gidx) {
    int bs = blockIdx.x;
    int b = bs >> 10;
    const float* xb = xyz + (size_t)b * 3 * N_;
    int ci = ct_idx[bs];
    float cx = xb[ci], cy = xb[N_ + ci], cz = xb[2 * N_ + ci];
    float cs = cx * cx + cy * cy + cz * cz;
    int t = threadIdx.x;
    unsigned long long pk[16];
#pragma unroll
    for (int j = 0; j < 16; j++) {
        int n = j * 256 + t;
        float x = xb[n], y = xb[N_ + n], z = xb[2 * N_ + n];
        float xn = x * x + y * y + z * z;
        float dot = cx * x + cy * y + cz * z;
        float val = cs + xn - 2.f * dot;        // reference formula order
        unsigned vb = __float_as_uint(val);
        unsigned key = (vb & 0x80000000u) ? ~vb : (vb | 0x80000000u);
        pk[j] = ((unsigned long long)key << 32) | (unsigned)n;
    }
    __shared__ unsigned long long sw[2][4];
    int out_base = bs * NS_;
    int w = t >> 6;
    for (int iter = 0; iter < NS_; iter++) {
        unsigned long long m8[8], m4[4];
#pragma unroll
        for (int j = 0; j < 8; j++) m8[j] = pk[2 * j] < pk[2 * j + 1] ? pk[2 * j] : pk[2 * j + 1];
#pragma unroll
        for (int j = 0; j < 4; j++) m4[j] = m8[2 * j] < m8[2 * j + 1] ? m8[2 * j] : m8[2 * j + 1];
        unsigned long long ma = m4[0] < m4[1] ? m4[0] : m4[1];
        unsigned long long mb = m4[2] < m4[3] ? m4[2] : m4[3];
        unsigned long long best = ma < mb ? ma : mb;
        unsigned hi = (unsigned)(best >> 32), lo = (unsigned)best;
        dpp_min_u64(hi, lo);
        int p = iter & 1;
        if ((t & 63) == 63) sw[p][w] = ((unsigned long long)hi << 32) | lo;
        __syncthreads();
        unsigned long long b0 = sw[p][0], b1 = sw[p][1], b2 = sw[p][2], b3 = sw[p][3];
        unsigned long long wa = b0 < b1 ? b0 : b1;
        unsigned long long wb = b2 < b3 ? b2 : b3;
        unsigned long long bw = wa < wb ? wa : wb;
        int n = (int)(unsigned)(bw & 0xffffffffu);
        if (t == 0) gidx[out_base + iter] = n;
        if ((n & 255) == t) pk[n >> 8] = 0xFFFFFFFF00000000ull | (unsigned)n;
        // parity double-buffer: no trailing barrier needed
    }
}

// ---------------------------------------------------------------- ct_p output
__global__ __launch_bounds__(256) void ctp_kernel(const float* __restrict__ xyz,
                                                  const int* __restrict__ ct_idx,
                                                  float* __restrict__ out) {
    int i = blockIdx.x * 256 + threadIdx.x;
    if (i >= B_ * 3 * S_) return;
    int b = i / (3 * S_);
    int rem = i - b * 3 * S_;
    int c = rem >> 10;
    int s = rem & (S_ - 1);
    int ci = ct_idx[b * S_ + s];
    out[i] = xyz[(size_t)b * 3 * N_ + (size_t)c * N_ + ci];
}

// ---------------------------------------------------------------- gather -> ft [33][R]
// ch 0-2: rel xyz; ch 3-31: points; ch 32: rd
__global__ __launch_bounds__(256) void gather_kernel(const float* __restrict__ xyz,
                                                     const float* __restrict__ pts,
                                                     const int* __restrict__ ct_idx,
                                                     const int* __restrict__ gidx,
                                                     float* __restrict__ ft) {
    int r = blockIdx.x * 256 + threadIdx.x;
    int b = r >> 15;
    int s = (r >> 5) & (S_ - 1);
    int g = gidx[r];
    int ci = ct_idx[b * S_ + s];
    const float* xb = xyz + (size_t)b * 3 * N_;
    float rx = xb[g] - xb[ci];
    float ry = xb[N_ + g] - xb[N_ + ci];
    float rz = xb[2 * N_ + g] - xb[2 * N_ + ci];
    ft[r] = rx;
    ft[(size_t)R_ + r] = ry;
    ft[(size_t)2 * R_ + r] = rz;
    float rd = sqrtf(fmaxf(rx * rx + ry * ry + rz * rz, 1e-12f));
    ft[(size_t)32 * R_ + r] = rd;
    const float* pb = pts + (size_t)b * 29 * N_;
#pragma unroll
    for (int c = 0; c < 29; c++) ft[(size_t)(3 + c) * R_ + r] = pb[(size_t)c * N_ + g];
}

// ---------------------------------------------------------------- conv1x1 (+optional input BN-affine+relu)
// 64 output channels per y-block; 2 rows per thread; weights broadcast from LDS.
// Fused BN-stats epilogue: per-block per-channel (sum, sumsq) via DPP wave sums
// -> partial[(c)*1024 + bx] (s) and [(c)*1024 + 512 + bx] (q). Deterministic.
template <int CIN, bool AFF>
__global__ __launch_bounds__(256) void convk(const float* __restrict__ xin,
                                             const float* __restrict__ W,
                                             const float* __restrict__ bias,
                                             const float* __restrict__ ab,
                                             float* __restrict__ out0,
                                             float* __restrict__ out1,
                                             float* __restrict__ partial) {
    __shared__ float Ws[CIN][64];
    __shared__ float bs_[64];
    __shared__ float as_[CIN], bbs[CIN];
    __shared__ float red[4][64][2];
    int oc0 = blockIdx.y * 64;
    for (int i = threadIdx.x; i < CIN * 64; i += 256) {
        int o = i & 63, c = i >> 6;
        Ws[c][o] = W[(size_t)(oc0 + o) * CIN + c];
    }
    if (threadIdx.x < 64) bs_[threadIdx.x] = bias[oc0 + threadIdx.x];
    if (AFF) {
        for (int i = threadIdx.x; i < CIN; i += 256) { as_[i] = ab[i]; bbs[i] = ab[CIN + i]; }
    }
    __syncthreads();
    size_t r0 = (size_t)blockIdx.x * 512 + threadIdx.x;
    float acc0[64], acc1[64];
#pragma unroll
    for (int o = 0; o < 64; o++) { acc0[o] = 0.f; acc1[o] = 0.f; }
    for (int c = 0; c < CIN; c++) {
        float x0 = xin[(size_t)c * R_ + r0];
        float x1 = xin[(size_t)c * R_ + r0 + 256];
        if (AFF) {
            float a = as_[c], bb = bbs[c];
            x0 = fmaxf(fmaf(a, x0, bb), 0.f);
            x1 = fmaxf(fmaf(a, x1, bb), 0.f);
        }
#pragma unroll
        for (int o = 0; o < 64; o++) {
            float w = Ws[c][o];
            acc0[o] = fmaf(x0, w, acc0[o]);
            acc1[o] = fmaf(x1, w, acc1[o]);
        }
    }
    float* outp = blockIdx.y ? out1 : out0;
    int wv = threadIdx.x >> 6;
#pragma unroll
    for (int o = 0; o < 64; o++) {
        float bv = bs_[o];
        float y0 = acc0[o] + bv;
        float y1 = acc1[o] + bv;
        outp[(size_t)o * R_ + r0] = y0;
        outp[(size_t)o * R_ + r0 + 256] = y1;
        float s = y0 + y1;
        float q = fmaf(y0, y0, y1 * y1);
        s = dpp_sum_f32(s);
        q = dpp_sum_f32(q);
        if ((threadIdx.x & 63) == 63) { red[wv][o][0] = s; red[wv][o][1] = q; }
    }
    __syncthreads();
    if (threadIdx.x < 64) {
        int o = threadIdx.x;
        float s = red[0][o][0] + red[1][o][0] + red[2][o][0] + red[3][o][0];
        float q = red[0][o][1] + red[1][o][1] + red[2][o][1] + red[3][o][1];
        partial[(size_t)(oc0 + o) * 1024 + blockIdx.x] = s;
        partial[(size_t)(oc0 + o) * 1024 + 512 + blockIdx.x] = q;
    }
}

// conv1 branch: 4 input channels = ft{0,1,2,32} (rel xyz + rd), fused stats
__global__ __launch_bounds__(256) void conv1_kernel(const float* __restrict__ ft,
                                                    const float* __restrict__ W,
                                                    const float* __restrict__ bias,
                                                    float* __restrict__ out,
                                                    float* __restrict__ partial) {
    __shared__ float Ws[4][64];
    __shared__ float bs_[64];
    __shared__ float red[4][64][2];
    {
        int i = threadIdx.x;
        if (i < 256) { int o = i & 63, c = i >> 6; Ws[c][o] = W[o * 4 + c]; }
    }
    if (threadIdx.x < 64) bs_[threadIdx.x] = bias[threadIdx.x];
    __syncthreads();
    size_t r0 = (size_t)blockIdx.x * 512 + threadIdx.x;
    float acc0[64], acc1[64];
#pragma unroll
    for (int o = 0; o < 64; o++) { acc0[o] = 0.f; acc1[o] = 0.f; }
    const int chs[4] = {0, 1, 2, 32};
#pragma unroll
    for (int c = 0; c < 4; c++) {
        int ch = chs[c];
        float x0 = ft[(size_t)ch * R_ + r0];
        float x1 = ft[(size_t)ch * R_ + r0 + 256];
#pragma unroll
        for (int o = 0; o < 64; o++) {
            float w = Ws[c][o];
            acc0[o] = fmaf(x0, w, acc0[o]);
            acc1[o] = fmaf(x1, w, acc1[o]);
        }
    }
    int wv = threadIdx.x >> 6;
#pragma unroll
    for (int o = 0; o < 64; o++) {
        float bv = bs_[o];
        float y0 = acc0[o] + bv;
        float y1 = acc1[o] + bv;
        out[(size_t)o * R_ + r0] = y0;
        out[(size_t)o * R_ + r0 + 256] = y1;
        float s = y0 + y1;
        float q = fmaf(y0, y0, y1 * y1);
        s = dpp_sum_f32(s);
        q = dpp_sum_f32(q);
        if ((threadIdx.x & 63) == 63) { red[wv][o][0] = s; red[wv][o][1] = q; }
    }
    __syncthreads();
    if (threadIdx.x < 64) {
        int o = threadIdx.x;
        float s = red[0][o][0] + red[1][o][0] + red[2][o][0] + red[3][o][0];
        float q = red[0][o][1] + red[1][o][1] + red[2][o][1] + red[3][o][1];
        partial[(size_t)o * 1024 + blockIdx.x] = s;
        partial[(size_t)o * 1024 + 512 + blockIdx.x] = q;
    }
}

// ---------------------------------------------------------------- BN finalize
// One wave per channel: reduce 512 block partials (s and q), emit affine (a,b).
__global__ __launch_bounds__(64) void statsf(const float* __restrict__ partial,
                                             const float* __restrict__ g,
                                             const float* __restrict__ be,
                                             float* __restrict__ ab, int C) {
    int c = blockIdx.x, t = threadIdx.x;
    float s = 0.f, q = 0.f;
    for (int i = t; i < 512; i += 64) {
        s += partial[(size_t)c * 1024 + i];
        q += partial[(size_t)c * 1024 + 512 + i];
    }
    s = dpp_sum_f32(s);
    q = dpp_sum_f32(q);
    if (t == 63) {
        float inv = 1.0f / (float)R_;
        float mean = s * inv;
        float var = q * inv - mean * mean;
        float a = g[c] / sqrtf(var + EPS_);
        ab[c] = a;
        ab[C + c] = be[c] - mean * a;
    }
}

// ---------------------------------------------------------------- epilogues
__global__ __launch_bounds__(128) void final_max(const float* __restrict__ yA,
                                                 const float* __restrict__ yC,
                                                 const float* __restrict__ ab,
                                                 float* __restrict__ out) {
    int bs = blockIdx.x;
    int c = threadIdx.x;
    const float* src = (c < 64 ? yA + (size_t)c * R_ : yC + (size_t)(c - 64) * R_) + (size_t)bs * NS_;
    float a = ab[c], bb = ab[128 + c];
    const float4* s4 = reinterpret_cast<const float4*>(src);
    float m = -FLT_MAX;
#pragma unroll
    for (int i = 0; i < 8; i++) {
        float4 v = s4[i];
        m = fmaxf(m, fmaxf(fmaf(a, v.x, bb), 0.f));
        m = fmaxf(m, fmaxf(fmaf(a, v.y, bb), 0.f));
        m = fmaxf(m, fmaxf(fmaf(a, v.z, bb), 0.f));
        m = fmaxf(m, fmaxf(fmaf(a, v.w, bb), 0.f));
    }
    int b = bs >> 10, s = bs & (S_ - 1);
    out[24576 + (size_t)b * 393216 + (size_t)c * 1024 + s] = m;
}

__global__ __launch_bounds__(128) void final_meanmax(const float* __restrict__ z1,
                                                     const float* __restrict__ z2,
                                                     const float* __restrict__ ab1,
                                                     const float* __restrict__ ab2,
                                                     float* __restrict__ out) {
    int bs = blockIdx.x;
    int c = threadIdx.x;
    const float* src;
    float a, bb;
    if (c < 64) { src = z1 + (size_t)c * R_; a = ab1[c]; bb = ab1[64 + c]; }
    else        { src = z2 + (size_t)(c - 64) * R_; a = ab2[c - 64]; bb = ab2[64 + (c - 64)]; }
    src += (size_t)bs * NS_;
    const float4* s4 = reinterpret_cast<const float4*>(src);
    float m = -FLT_MAX, sm = 0.f;
#pragma unroll
    for (int i = 0; i < 8; i++) {
        float4 v = s4[i];
        float t0 = fmaxf(fmaf(a, v.x, bb), 0.f); sm += t0; m = fmaxf(m, t0);
        float t1 = fmaxf(fmaf(a, v.y, bb), 0.f); sm += t1; m = fmaxf(m, t1);
        float t2 = fmaxf(fmaf(a, v.z, bb), 0.f); sm += t2; m = fmaxf(m, t2);
        float t3 = fmaxf(fmaf(a, v.w, bb), 0.f); sm += t3; m = fmaxf(m, t3);
    }
    int b = bs >> 10, s = bs & (S_ - 1);
    size_t ob = 24576 + (size_t)b * 393216;
    out[ob + (size_t)(128 + c) * 1024 + s] = sm * 0.03125f;
    out[ob + (size_t)(256 + c) * 1024 + s] = m;
}

// ================================================================ launch
extern "C" void kernel_launch(void* const* d_in, const int* in_sizes, int n_in,
                              void* d_out, int out_size, void* d_ws, size_t ws_size,
                              hipStream_t stream) {
    const float* xyz = (const float*)d_in[0];
    const float* pts = (const float*)d_in[1];
    const float* W0 = (const float*)d_in[2];  const float* b0 = (const float*)d_in[3];
    const float* g0 = (const float*)d_in[4];  const float* be0 = (const float*)d_in[5];
    const float* W1 = (const float*)d_in[6];  const float* b1 = (const float*)d_in[7];
    const float* g1 = (const float*)d_in[8];  const float* be1 = (const float*)d_in[9];
    const float* W2 = (const float*)d_in[10]; const float* b2 = (const float*)d_in[11];
    const float* g2 = (const float*)d_in[12]; const float* be2 = (const float*)d_in[13];
    const float* c1w = (const float*)d_in[14]; const float* c1b = (const float*)d_in[15];
    const float* bg1 = (const float*)d_in[16]; const float* bbe1 = (const float*)d_in[17];
    const float* c2w = (const float*)d_in[18]; const float* c2b = (const float*)d_in[19];
    const float* bg2 = (const float*)d_in[20]; const float* bbe2 = (const float*)d_in[21];
    float* out = (float*)d_out;

    // workspace layout (floats after the two int arrays)
    int* ct_idx = (int*)d_ws;                       // [8192]
    int* gidx = ct_idx + B_ * S_;                   // [262144]
    float* fbase = (float*)d_ws;
    float* ft = fbase + 270336;                     // 33*R
    float* A = ft + (size_t)33 * R_;                // 64*R   (y0 -> y2.lo -> z1)
    float* Bb = A + (size_t)64 * R_;                // 64*R   (y1 -> z2)
    float* C = Bb + (size_t)64 * R_;                // 64*R   (y2.hi)
    float* partial = C + (size_t)64 * R_;           // 128*1024
    float* ab0 = partial + 131072;                  // 128
    float* ab1 = ab0 + 128;                         // 128
    float* ab2 = ab1 + 128;                         // 256
    float* abz1 = ab2 + 256;                        // 128
    float* abz2 = abz1 + 128;                       // 128

    fps_kernel<<<B_, 512, 0, stream>>>(xyz, ct_idx);
    knn_kernel<<<B_ * S_, 256, 0, stream>>>(xyz, ct_idx, gidx);
    ctp_kernel<<<(B_ * 3 * S_ + 255) / 256, 256, 0, stream>>>(xyz, ct_idx, out);
    gather_kernel<<<R_ / 256, 256, 0, stream>>>(xyz, pts, ct_idx, gidx, ft);

    // MLP stack (stats fused into conv epilogues)
    convk<32, false><<<dim3(R_ / 512, 1), 256, 0, stream>>>(ft, W0, b0, nullptr, A, nullptr, partial);
    statsf<<<64, 64, 0, stream>>>(partial, g0, be0, ab0, 64);
    convk<64, true><<<dim3(R_ / 512, 1), 256, 0, stream>>>(A, W1, b1, ab0, Bb, nullptr, partial);
    statsf<<<64, 64, 0, stream>>>(partial, g1, be1, ab1, 64);
    convk<64, true><<<dim3(R_ / 512, 2), 256, 0, stream>>>(Bb, W2, b2, ab1, A, C, partial);
    statsf<<<128, 64, 0, stream>>>(partial, g2, be2, ab2, 128);
    final_max<<<B_ * S_, 128, 0, stream>>>(A, C, ab2, out);

    // conv2 branch (ft -> z2 in Bb)
    convk<32, false><<<dim3(R_ / 512, 1), 256, 0, stream>>>(ft, c2w, c2b, nullptr, Bb, nullptr, partial);
    statsf<<<64, 64, 0, stream>>>(partial, bg2, bbe2, abz2, 64);

    // conv1 branch (ft{0,1,2,32} -> z1 in A; A free after final_max)
    conv1_kernel<<<R_ / 512, 256, 0, stream>>>(ft, c1w, c1b, A, partial);
    statsf<<<64, 64, 0, stream>>>(partial, bg1, bbe1, abz1, 64);

    final_meanmax<<<B_ * S_, 128, 0, stream>>>(A, Bb, abz1, abz2, out);
}

// Round 5
// 1513.433 us; speedup vs baseline: 1.0301x; 1.0301x over previous
//
#include <hip/hip_runtime.h>
#include <cfloat>
#include <math.h>

constexpr int B_ = 8, N_ = 4096, S_ = 1024, NS_ = 32;
constexpr int R_ = B_ * S_ * NS_;          // 262144 rows (b,s,k)
constexpr float EPS_ = 1e-5f;

// ---------------------------------------------------------------- DPP helpers
// u32 max across wave, result valid in lane 63.
__device__ __forceinline__ unsigned dpp_red_umax(unsigned x) {
    unsigned t;
#define STEP_(ctrl) t = (unsigned)__builtin_amdgcn_update_dpp((int)x, (int)x, ctrl, 0xf, 0xf, false); x = x > t ? x : t;
    STEP_(0x111) STEP_(0x112) STEP_(0x114) STEP_(0x118) STEP_(0x142) STEP_(0x143)
#undef STEP_
    return x;
}
__device__ __forceinline__ void dpp_min_u64(unsigned& hi, unsigned& lo) {
#define STEP_(ctrl) { \
    unsigned h2 = (unsigned)__builtin_amdgcn_update_dpp((int)hi, (int)hi, ctrl, 0xf, 0xf, false); \
    unsigned l2 = (unsigned)__builtin_amdgcn_update_dpp((int)lo, (int)lo, ctrl, 0xf, 0xf, false); \
    if (h2 < hi || (h2 == hi && l2 < lo)) { hi = h2; lo = l2; } }
    STEP_(0x111) STEP_(0x112) STEP_(0x114) STEP_(0x118) STEP_(0x142) STEP_(0x143)
#undef STEP_
}
// f32 wave sum (canonical shr/bcast sequence), result valid in lane 63.
__device__ __forceinline__ float dpp_sum_f32(float x) {
#define ADD_(ctrl, rm) { \
    int t_ = __builtin_amdgcn_update_dpp(0, __float_as_int(x), ctrl, rm, 0xf, true); \
    x += __int_as_float(t_); }
    ADD_(0x111, 0xf) ADD_(0x112, 0xf) ADD_(0x114, 0xf) ADD_(0x118, 0xf)
    ADD_(0x142, 0xa) ADD_(0x143, 0xc)
#undef ADD_
    return x;
}

// ---------------------------------------------------------------- FPS
// One block per batch, 256 threads x 16 CONTIGUOUS points (n = t*16 + j).
// Exact reference semantics: ct_idx[0]=0; dist=min(dist,d); argmax with
// first-index tie-break. Per-iter: local argmax tree (>= keeps lower j) ->
// DPP u32 max -> scalar resolve (ballot + s_ff1 + readlane: smallest wave ->
// smallest lane -> smallest j == smallest n) -> 4-entry u64 LDS combine
// (parity double-buffer, single barrier).
__global__ __launch_bounds__(256) void fps_kernel(const float* __restrict__ xyz,
                                                  int* __restrict__ ct_idx) {
    int b = blockIdx.x;
    const float* xb = xyz + (size_t)b * 3 * N_;
    int t = threadIdx.x;
    __shared__ float sx[N_], sy[N_], sz[N_];
    __shared__ unsigned long long sb[2][4];
    for (int i = t; i < N_; i += 256) {
        sx[i] = xb[i];
        sy[i] = xb[N_ + i];
        sz[i] = xb[2 * N_ + i];
    }
    float px[16], py[16], pz[16], dist[16];
#pragma unroll
    for (int j = 0; j < 16; j++) {
        int n = t * 16 + j;                 // contiguous ownership
        px[j] = xb[n];
        py[j] = xb[N_ + n];
        pz[j] = xb[2 * N_ + n];
        dist[j] = 1e10f;
    }
    __syncthreads();
    float cx = sx[0], cy = sy[0], cz = sz[0];
    int far = 0;
    int w = t >> 6;
    for (int it = 0; it < S_; it++) {
        if (t == 0) ct_idx[b * S_ + it] = far;
#pragma unroll
        for (int j = 0; j < 16; j++) {
            float dx = px[j] - cx, dy = py[j] - cy, dz = pz[j] - cz;
            float d = dx * dx;
            d = fmaf(dy, dy, d);
            d = fmaf(dz, dz, d);              // same value chain as passing version
            dist[j] = fminf(dist[j], d);
        }
        // local argmax tree, >= keeps the lower index on ties
        float v8[8], v4[4], v2[2];
        int j8[8], j4[4], j2[2];
#pragma unroll
        for (int j = 0; j < 8; j++) {
            bool ge = dist[2 * j] >= dist[2 * j + 1];
            v8[j] = ge ? dist[2 * j] : dist[2 * j + 1];
            j8[j] = ge ? 2 * j : 2 * j + 1;
        }
#pragma unroll
        for (int j = 0; j < 4; j++) {
            bool ge = v8[2 * j] >= v8[2 * j + 1];
            v4[j] = ge ? v8[2 * j] : v8[2 * j + 1];
            j4[j] = ge ? j8[2 * j] : j8[2 * j + 1];
        }
#pragma unroll
        for (int j = 0; j < 2; j++) {
            bool ge = v4[2 * j] >= v4[2 * j + 1];
            v2[j] = ge ? v4[2 * j] : v4[2 * j + 1];
            j2[j] = ge ? j4[2 * j] : j4[2 * j + 1];
        }
        bool ge0 = v2[0] >= v2[1];
        float lmax = ge0 ? v2[0] : v2[1];
        int jbest = ge0 ? j2[0] : j2[1];
        // wave max (nonneg f32 bits order as u32)
        unsigned wm = (unsigned)__builtin_amdgcn_readlane(
            (int)dpp_red_umax(__float_as_uint(lmax)), 63);
        // scalar index resolve: first lane holding wm, then its first j
        unsigned long long lanes = __ballot(__float_as_uint(lmax) == wm);
        int l = __ffsll(lanes) - 1;           // >=0: wave max exists in-wave
        int js = __builtin_amdgcn_readlane(jbest, l);
        unsigned n = (unsigned)(((w << 6) + l) * 16 + js);
        int p = it & 1;
        if ((t & 63) == 0)
            sb[p][w] = ((unsigned long long)wm << 32) | (unsigned)~n;
        __syncthreads();
        unsigned long long b0 = sb[p][0], b1 = sb[p][1], b2 = sb[p][2], b3 = sb[p][3];
        unsigned long long ma = b0 > b1 ? b0 : b1;
        unsigned long long mb = b2 > b3 ? b2 : b3;
        unsigned long long bw = ma > mb ? ma : mb;
        far = (int)(~(unsigned)(bw & 0xffffffffu)) & (N_ - 1);
        cx = sx[far]; cy = sy[far]; cz = sz[far];
        // no trailing barrier: next iter writes the OTHER parity buffer; a wave
        // reaches iter+2's write only after all waves passed iter+1's barrier.
    }
}

// ---------------------------------------------------------------- kNN
// One block per (b,s). Order-preserving u32 keys precomputed once; per iter:
// u64 (key<<32)|idx min tree -> DPP u64 min -> 4-entry LDS combine (parity,
// single barrier). Tie -> smaller index (= lax.top_k selection set).
__global__ __launch_bounds__(256) void knn_kernel(const float* __restrict__ xyz,
                                                  const int* __restrict__ ct_idx,
                                                  int* __restrict__ gidx) {
    int bs = blockIdx.x;
    int b = bs >> 10;
    const float* xb = xyz + (size_t)b * 3 * N_;
    int ci = ct_idx[bs];
    float cx = xb[ci], cy = xb[N_ + ci], cz = xb[2 * N_ + ci];
    float cs = cx * cx + cy * cy + cz * cz;
    int t = threadIdx.x;
    unsigned long long pk[16];
#pragma unroll
    for (int j = 0; j < 16; j++) {
        int n = j * 256 + t;
        float x = xb[n], y = xb[N_ + n], z = xb[2 * N_ + n];
        float xn = x * x + y * y + z * z;
        float dot = cx * x + cy * y + cz * z;
        float val = cs + xn - 2.f * dot;        // reference formula order
        unsigned vb = __float_as_uint(val);
        unsigned key = (vb & 0x80000000u) ? ~vb : (vb | 0x80000000u);
        pk[j] = ((unsigned long long)key << 32) | (unsigned)n;
    }
    __shared__ unsigned long long sw[2][4];
    int out_base = bs * NS_;
    int w = t >> 6;
    for (int iter = 0; iter < NS_; iter++) {
        unsigned long long m8[8], m4[4];
#pragma unroll
        for (int j = 0; j < 8; j++) m8[j] = pk[2 * j] < pk[2 * j + 1] ? pk[2 * j] : pk[2 * j + 1];
#pragma unroll
        for (int j = 0; j < 4; j++) m4[j] = m8[2 * j] < m8[2 * j + 1] ? m8[2 * j] : m8[2 * j + 1];
        unsigned long long ma = m4[0] < m4[1] ? m4[0] : m4[1];
        unsigned long long mb = m4[2] < m4[3] ? m4[2] : m4[3];
        unsigned long long best = ma < mb ? ma : mb;
        unsigned hi = (unsigned)(best >> 32), lo = (unsigned)best;
        dpp_min_u64(hi, lo);
        int p = iter & 1;
        if ((t & 63) == 63) sw[p][w] = ((unsigned long long)hi << 32) | lo;
        __syncthreads();
        unsigned long long b0 = sw[p][0], b1 = sw[p][1], b2 = sw[p][2], b3 = sw[p][3];
        unsigned long long wa = b0 < b1 ? b0 : b1;
        unsigned long long wb = b2 < b3 ? b2 : b3;
        unsigned long long bw = wa < wb ? wa : wb;
        int n = (int)(unsigned)(bw & 0xffffffffu);
        if (t == 0) gidx[out_base + iter] = n;
        if ((n & 255) == t) pk[n >> 8] = 0xFFFFFFFF00000000ull | (unsigned)n;
        // parity double-buffer: no trailing barrier needed
    }
}

// ---------------------------------------------------------------- ct_p output
__global__ __launch_bounds__(256) void ctp_kernel(const float* __restrict__ xyz,
                                                  const int* __restrict__ ct_idx,
                                                  float* __restrict__ out) {
    int i = blockIdx.x * 256 + threadIdx.x;
    if (i >= B_ * 3 * S_) return;
    int b = i / (3 * S_);
    int rem = i - b * 3 * S_;
    int c = rem >> 10;
    int s = rem & (S_ - 1);
    int ci = ct_idx[b * S_ + s];
    out[i] = xyz[(size_t)b * 3 * N_ + (size_t)c * N_ + ci];
}

// ---------------------------------------------------------------- gather -> ft [33][R]
// ch 0-2: rel xyz; ch 3-31: points; ch 32: rd
__global__ __launch_bounds__(256) void gather_kernel(const float* __restrict__ xyz,
                                                     const float* __restrict__ pts,
                                                     const int* __restrict__ ct_idx,
                                                     const int* __restrict__ gidx,
                                                     float* __restrict__ ft) {
    int r = blockIdx.x * 256 + threadIdx.x;
    int b = r >> 15;
    int s = (r >> 5) & (S_ - 1);
    int g = gidx[r];
    int ci = ct_idx[b * S_ + s];
    const float* xb = xyz + (size_t)b * 3 * N_;
    float rx = xb[g] - xb[ci];
    float ry = xb[N_ + g] - xb[N_ + ci];
    float rz = xb[2 * N_ + g] - xb[2 * N_ + ci];
    ft[r] = rx;
    ft[(size_t)R_ + r] = ry;
    ft[(size_t)2 * R_ + r] = rz;
    float rd = sqrtf(fmaxf(rx * rx + ry * ry + rz * rz, 1e-12f));
    ft[(size_t)32 * R_ + r] = rd;
    const float* pb = pts + (size_t)b * 29 * N_;
#pragma unroll
    for (int c = 0; c < 29; c++) ft[(size_t)(3 + c) * R_ + r] = pb[(size_t)c * N_ + g];
}

// ---------------------------------------------------------------- conv1x1 (+optional input BN-affine+relu)
// 64 output channels per y-block; 2 rows per thread; weights broadcast from LDS.
// Fused BN-stats epilogue: per-block per-channel (sum, sumsq) via DPP wave sums
// -> partial[(c)*1024 + bx] (s) and [(c)*1024 + 512 + bx] (q). Deterministic.
template <int CIN, bool AFF>
__global__ __launch_bounds__(256) void convk(const float* __restrict__ xin,
                                             const float* __restrict__ W,
                                             const float* __restrict__ bias,
                                             const float* __restrict__ ab,
                                             float* __restrict__ out0,
                                             float* __restrict__ out1,
                                             float* __restrict__ partial) {
    __shared__ float Ws[CIN][64];
    __shared__ float bs_[64];
    __shared__ float as_[CIN], bbs[CIN];
    __shared__ float red[4][64][2];
    int oc0 = blockIdx.y * 64;
    for (int i = threadIdx.x; i < CIN * 64; i += 256) {
        int o = i & 63, c = i >> 6;
        Ws[c][o] = W[(size_t)(oc0 + o) * CIN + c];
    }
    if (threadIdx.x < 64) bs_[threadIdx.x] = bias[oc0 + threadIdx.x];
    if (AFF) {
        for (int i = threadIdx.x; i < CIN; i += 256) { as_[i] = ab[i]; bbs[i] = ab[CIN + i]; }
    }
    __syncthreads();
    size_t r0 = (size_t)blockIdx.x * 512 + threadIdx.x;
    float acc0[64], acc1[64];
#pragma unroll
    for (int o = 0; o < 64; o++) { acc0[o] = 0.f; acc1[o] = 0.f; }
    for (int c = 0; c < CIN; c++) {
        float x0 = xin[(size_t)c * R_ + r0];
        float x1 = xin[(size_t)c * R_ + r0 + 256];
        if (AFF) {
            float a = as_[c], bb = bbs[c];
            x0 = fmaxf(fmaf(a, x0, bb), 0.f);
            x1 = fmaxf(fmaf(a, x1, bb), 0.f);
        }
#pragma unroll
        for (int o = 0; o < 64; o++) {
            float w = Ws[c][o];
            acc0[o] = fmaf(x0, w, acc0[o]);
            acc1[o] = fmaf(x1, w, acc1[o]);
        }
    }
    float* outp = blockIdx.y ? out1 : out0;
    int wv = threadIdx.x >> 6;
#pragma unroll
    for (int o = 0; o < 64; o++) {
        float bv = bs_[o];
        float y0 = acc0[o] + bv;
        float y1 = acc1[o] + bv;
        outp[(size_t)o * R_ + r0] = y0;
        outp[(size_t)o * R_ + r0 + 256] = y1;
        float s = y0 + y1;
        float q = fmaf(y0, y0, y1 * y1);
        s = dpp_sum_f32(s);
        q = dpp_sum_f32(q);
        if ((threadIdx.x & 63) == 63) { red[wv][o][0] = s; red[wv][o][1] = q; }
    }
    __syncthreads();
    if (threadIdx.x < 64) {
        int o = threadIdx.x;
        float s = red[0][o][0] + red[1][o][0] + red[2][o][0] + red[3][o][0];
        float q = red[0][o][1] + red[1][o][1] + red[2][o][1] + red[3][o][1];
        partial[(size_t)(oc0 + o) * 1024 + blockIdx.x] = s;
        partial[(size_t)(oc0 + o) * 1024 + 512 + blockIdx.x] = q;
    }
}

// conv1 branch: 4 input channels = ft{0,1,2,32} (rel xyz + rd), fused stats
__global__ __launch_bounds__(256) void conv1_kernel(const float* __restrict__ ft,
                                                    const float* __restrict__ W,
                                                    const float* __restrict__ bias,
                                                    float* __restrict__ out,
                                                    float* __restrict__ partial) {
    __shared__ float Ws[4][64];
    __shared__ float bs_[64];
    __shared__ float red[4][64][2];
    {
        int i = threadIdx.x;
        if (i < 256) { int o = i & 63, c = i >> 6; Ws[c][o] = W[o * 4 + c]; }
    }
    if (threadIdx.x < 64) bs_[threadIdx.x] = bias[threadIdx.x];
    __syncthreads();
    size_t r0 = (size_t)blockIdx.x * 512 + threadIdx.x;
    float acc0[64], acc1[64];
#pragma unroll
    for (int o = 0; o < 64; o++) { acc0[o] = 0.f; acc1[o] = 0.f; }
    const int chs[4] = {0, 1, 2, 32};
#pragma unroll
    for (int c = 0; c < 4; c++) {
        int ch = chs[c];
        float x0 = ft[(size_t)ch * R_ + r0];
        float x1 = ft[(size_t)ch * R_ + r0 + 256];
#pragma unroll
        for (int o = 0; o < 64; o++) {
            float w = Ws[c][o];
            acc0[o] = fmaf(x0, w, acc0[o]);
            acc1[o] = fmaf(x1, w, acc1[o]);
        }
    }
    int wv = threadIdx.x >> 6;
#pragma unroll
    for (int o = 0; o < 64; o++) {
        float bv = bs_[o];
        float y0 = acc0[o] + bv;
        float y1 = acc1[o] + bv;
        out[(size_t)o * R_ + r0] = y0;
        out[(size_t)o * R_ + r0 + 256] = y1;
        float s = y0 + y1;
        float q = fmaf(y0, y0, y1 * y1);
        s = dpp_sum_f32(s);
        q = dpp_sum_f32(q);
        if ((threadIdx.x & 63) == 63) { red[wv][o][0] = s; red[wv][o][1] = q; }
    }
    __syncthreads();
    if (threadIdx.x < 64) {
        int o = threadIdx.x;
        float s = red[0][o][0] + red[1][o][0] + red[2][o][0] + red[3][o][0];
        float q = red[0][o][1] + red[1][o][1] + red[2][o][1] + red[3][o][1];
        partial[(size_t)o * 1024 + blockIdx.x] = s;
        partial[(size_t)o * 1024 + 512 + blockIdx.x] = q;
    }
}

// ---------------------------------------------------------------- BN finalize
// One wave per channel: reduce 512 block partials (s and q), emit affine (a,b).
__global__ __launch_bounds__(64) void statsf(const float* __restrict__ partial,
                                             const float* __restrict__ g,
                                             const float* __restrict__ be,
                                             float* __restrict__ ab, int C) {
    int c = blockIdx.x, t = threadIdx.x;
    float s = 0.f, q = 0.f;
    for (int i = t; i < 512; i += 64) {
        s += partial[(size_t)c * 1024 + i];
        q += partial[(size_t)c * 1024 + 512 + i];
    }
    s = dpp_sum_f32(s);
    q = dpp_sum_f32(q);
    if (t == 63) {
        float inv = 1.0f / (float)R_;
        float mean = s * inv;
        float var = q * inv - mean * mean;
        float a = g[c] / sqrtf(var + EPS_);
        ab[c] = a;
        ab[C + c] = be[c] - mean * a;
    }
}

// ---------------------------------------------------------------- epilogues
__global__ __launch_bounds__(128) void final_max(const float* __restrict__ yA,
                                                 const float* __restrict__ yC,
                                                 const float* __restrict__ ab,
                                                 float* __restrict__ out) {
    int bs = blockIdx.x;
    int c = threadIdx.x;
    const float* src = (c < 64 ? yA + (size_t)c * R_ : yC + (size_t)(c - 64) * R_) + (size_t)bs * NS_;
    float a = ab[c], bb = ab[128 + c];
    const float4* s4 = reinterpret_cast<const float4*>(src);
    float m = -FLT_MAX;
#pragma unroll
    for (int i = 0; i < 8; i++) {
        float4 v = s4[i];
        m = fmaxf(m, fmaxf(fmaf(a, v.x, bb), 0.f));
        m = fmaxf(m, fmaxf(fmaf(a, v.y, bb), 0.f));
        m = fmaxf(m, fmaxf(fmaf(a, v.z, bb), 0.f));
        m = fmaxf(m, fmaxf(fmaf(a, v.w, bb), 0.f));
    }
    int b = bs >> 10, s = bs & (S_ - 1);
    out[24576 + (size_t)b * 393216 + (size_t)c * 1024 + s] = m;
}

__global__ __launch_bounds__(128) void final_meanmax(const float* __restrict__ z1,
                                                     const float* __restrict__ z2,
                                                     const float* __restrict__ ab1,
                                                     const float* __restrict__ ab2,
                                                     float* __restrict__ out) {
    int bs = blockIdx.x;
    int c = threadIdx.x;
    const float* src;
    float a, bb;
    if (c < 64) { src = z1 + (size_t)c * R_; a = ab1[c]; bb = ab1[64 + c]; }
    else        { src = z2 + (size_t)(c - 64) * R_; a = ab2[c - 64]; bb = ab2[64 + (c - 64)]; }
    src += (size_t)bs * NS_;
    const float4* s4 = reinterpret_cast<const float4*>(src);
    float m = -FLT_MAX, sm = 0.f;
#pragma unroll
    for (int i = 0; i < 8; i++) {
        float4 v = s4[i];
        float t0 = fmaxf(fmaf(a, v.x, bb), 0.f); sm += t0; m = fmaxf(m, t0);
        float t1 = fmaxf(fmaf(a, v.y, bb), 0.f); sm += t1; m = fmaxf(m, t1);
        float t2 = fmaxf(fmaf(a, v.z, bb), 0.f); sm += t2; m = fmaxf(m, t2);
        float t3 = fmaxf(fmaf(a, v.w, bb), 0.f); sm += t3; m = fmaxf(m, t3);
    }
    int b = bs >> 10, s = bs & (S_ - 1);
    size_t ob = 24576 + (size_t)b * 393216;
    out[ob + (size_t)(128 + c) * 1024 + s] = sm * 0.03125f;
    out[ob + (size_t)(256 + c) * 1024 + s] = m;
}

// ================================================================ launch
extern "C" void kernel_launch(void* const* d_in, const int* in_sizes, int n_in,
                              void* d_out, int out_size, void* d_ws, size_t ws_size,
                              hipStream_t stream) {
    const float* xyz = (const float*)d_in[0];
    const float* pts = (const float*)d_in[1];
    const float* W0 = (const float*)d_in[2];  const float* b0 = (const float*)d_in[3];
    const float* g0 = (const float*)d_in[4];  const float* be0 = (const float*)d_in[5];
    const float* W1 = (const float*)d_in[6];  const float* b1 = (const float*)d_in[7];
    const float* g1 = (const float*)d_in[8];  const float* be1 = (const float*)d_in[9];
    const float* W2 = (const float*)d_in[10]; const float* b2 = (const float*)d_in[11];
    const float* g2 = (const float*)d_in[12]; const float* be2 = (const float*)d_in[13];
    const float* c1w = (const float*)d_in[14]; const float* c1b = (const float*)d_in[15];
    const float* bg1 = (const float*)d_in[16]; const float* bbe1 = (const float*)d_in[17];
    const float* c2w = (const float*)d_in[18]; const float* c2b = (const float*)d_in[19];
    const float* bg2 = (const float*)d_in[20]; const float* bbe2 = (const float*)d_in[21];
    float* out = (float*)d_out;

    // workspace layout (floats after the two int arrays)
    int* ct_idx = (int*)d_ws;                       // [8192]
    int* gidx = ct_idx + B_ * S_;                   // [262144]
    float* fbase = (float*)d_ws;
    float* ft = fbase + 270336;                     // 33*R
    float* A = ft + (size_t)33 * R_;                // 64*R   (y0 -> y2.lo -> z1)
    float* Bb = A + (size_t)64 * R_;                // 64*R   (y1 -> z2)
    float* C = Bb + (size_t)64 * R_;                // 64*R   (y2.hi)
    float* partial = C + (size_t)64 * R_;           // 128*1024
    float* ab0 = partial + 131072;                  // 128
    float* ab1 = ab0 + 128;                         // 128
    float* ab2 = ab1 + 128;                         // 256
    float* abz1 = ab2 + 256;                        // 128
    float* abz2 = abz1 + 128;                       // 128

    fps_kernel<<<B_, 256, 0, stream>>>(xyz, ct_idx);
    knn_kernel<<<B_ * S_, 256, 0, stream>>>(xyz, ct_idx, gidx);
    ctp_kernel<<<(B_ * 3 * S_ + 255) / 256, 256, 0, stream>>>(xyz, ct_idx, out);
    gather_kernel<<<R_ / 256, 256, 0, stream>>>(xyz, pts, ct_idx, gidx, ft);

    // MLP stack (stats fused into conv epilogues)
    convk<32, false><<<dim3(R_ / 512, 1), 256, 0, stream>>>(ft, W0, b0, nullptr, A, nullptr, partial);
    statsf<<<64, 64, 0, stream>>>(partial, g0, be0, ab0, 64);
    convk<64, true><<<dim3(R_ / 512, 1), 256, 0, stream>>>(A, W1, b1, ab0, Bb, nullptr, partial);
    statsf<<<64, 64, 0, stream>>>(partial, g1, be1, ab1, 64);
    convk<64, true><<<dim3(R_ / 512, 2), 256, 0, stream>>>(Bb, W2, b2, ab1, A, C, partial);
    statsf<<<128, 64, 0, stream>>>(partial, g2, be2, ab2, 128);
    final_max<<<B_ * S_, 128, 0, stream>>>(A, C, ab2, out);

    // conv2 branch (ft -> z2 in Bb)
    convk<32, false><<<dim3(R_ / 512, 1), 256, 0, stream>>>(ft, c2w, c2b, nullptr, Bb, nullptr, partial);
    statsf<<<64, 64, 0, stream>>>(partial, bg2, bbe2, abz2, 64);

    // conv1 branch (ft{0,1,2,32} -> z1 in A; A free after final_max)
    conv1_kernel<<<R_ / 512, 256, 0, stream>>>(ft, c1w, c1b, A, partial);
    statsf<<<64, 64, 0, stream>>>(partial, bg1, bbe1, abz1, 64);

    final_meanmax<<<B_ * S_, 128, 0, stream>>>(A, Bb, abz1, abz2, out);
}

// Round 7
// 1466.636 us; speedup vs baseline: 1.0630x; 1.0319x over previous
//
#include <hip/hip_runtime.h>
#include <cfloat>
#include <math.h>

constexpr int B_ = 8, N_ = 4096, S_ = 1024, NS_ = 32;
constexpr int R_ = B_ * S_ * NS_;          // 262144 rows (b,s,k)
constexpr float EPS_ = 1e-5f;

// ---------------------------------------------------------------- DPP helpers
// u32 max across wave, result valid in lane 63.
__device__ __forceinline__ unsigned dpp_red_umax(unsigned x) {
    unsigned t;
#define STEP_(ctrl) t = (unsigned)__builtin_amdgcn_update_dpp((int)x, (int)x, ctrl, 0xf, 0xf, false); x = x > t ? x : t;
    STEP_(0x111) STEP_(0x112) STEP_(0x114) STEP_(0x118) STEP_(0x142) STEP_(0x143)
#undef STEP_
    return x;
}
__device__ __forceinline__ unsigned dpp_red_umin(unsigned x) {
    unsigned t;
#define STEP_(ctrl) t = (unsigned)__builtin_amdgcn_update_dpp((int)x, (int)x, ctrl, 0xf, 0xf, false); x = x < t ? x : t;
    STEP_(0x111) STEP_(0x112) STEP_(0x114) STEP_(0x118) STEP_(0x142) STEP_(0x143)
#undef STEP_
    return x;
}
__device__ __forceinline__ void dpp_min_u64(unsigned& hi, unsigned& lo) {
#define STEP_(ctrl) { \
    unsigned h2 = (unsigned)__builtin_amdgcn_update_dpp((int)hi, (int)hi, ctrl, 0xf, 0xf, false); \
    unsigned l2 = (unsigned)__builtin_amdgcn_update_dpp((int)lo, (int)lo, ctrl, 0xf, 0xf, false); \
    if (h2 < hi || (h2 == hi && l2 < lo)) { hi = h2; lo = l2; } }
    STEP_(0x111) STEP_(0x112) STEP_(0x114) STEP_(0x118) STEP_(0x142) STEP_(0x143)
#undef STEP_
}
// f32 wave sum (canonical shr/bcast sequence), result valid in lane 63.
__device__ __forceinline__ float dpp_sum_f32(float x) {
#define ADD_(ctrl, rm) { \
    int t_ = __builtin_amdgcn_update_dpp(0, __float_as_int(x), ctrl, rm, 0xf, true); \
    x += __int_as_float(t_); }
    ADD_(0x111, 0xf) ADD_(0x112, 0xf) ADD_(0x114, 0xf) ADD_(0x118, 0xf)
    ADD_(0x142, 0xa) ADD_(0x143, 0xc)
#undef ADD_
    return x;
}

// ---------------------------------------------------------------- FPS
// One block per batch, 256 threads x 16 strided points (n = j*256 + t).
// Exact reference semantics: ct_idx[0]=0; dist=min(dist,d); argmax with
// first-index tie-break. Distance = SUBTRACT-form (bit-identical to the
// passing r3/r5 builds; dot-form flipped selections in r6 -> reverted).
// Structure: r3 two-phase 32-bit DPP reduce + balanced match tree, plus:
//  - no VMEM in the loop (selections staged in LDS, written once at end,
//    so __syncthreads' vmcnt(0) drain is free)
//  - centroid coords via one ds_read_b128 from interleaved float4 LDS.
__global__ __launch_bounds__(256) void fps_kernel(const float* __restrict__ xyz,
                                                  int* __restrict__ ct_idx) {
    int b = blockIdx.x;
    const float* xb = xyz + (size_t)b * 3 * N_;
    int t = threadIdx.x;
    __shared__ float4 sp[N_];                 // 64 KB interleaved coords
    __shared__ int sct[S_];                   // 4 KB staged selections
    __shared__ unsigned long long sb[2][4];
    for (int i = t; i < N_; i += 256) {
        float x = xb[i], y = xb[N_ + i], z = xb[2 * N_ + i];
        sp[i] = make_float4(x, y, z, 0.f);
    }
    float px[16], py[16], pz[16], dist[16];
    unsigned idxr[16];
#pragma unroll
    for (int j = 0; j < 16; j++) {
        int n = j * 256 + t;                  // strided: coalesced init loads
        px[j] = xb[n];
        py[j] = xb[N_ + n];
        pz[j] = xb[2 * N_ + n];
        dist[j] = 1e10f;
        idxr[j] = (unsigned)n;
    }
    __syncthreads();
    float4 c4 = sp[0];
    int far = 0;
    int w = t >> 6;
    for (int it = 0; it < S_; it++) {
        if (t == 0) sct[it] = far;
#pragma unroll
        for (int j = 0; j < 16; j++) {
            float dx = px[j] - c4.x, dy = py[j] - c4.y, dz = pz[j] - c4.z;
            float d = dx * dx;
            d = fmaf(dy, dy, d);
            d = fmaf(dz, dz, d);              // bit-identical to passing builds
            dist[j] = fminf(dist[j], d);
        }
        // balanced fmax tree over 16 local dists
        float v8[8], v4[4];
#pragma unroll
        for (int j = 0; j < 8; j++) v8[j] = fmaxf(dist[2 * j], dist[2 * j + 1]);
#pragma unroll
        for (int j = 0; j < 4; j++) v4[j] = fmaxf(v8[2 * j], v8[2 * j + 1]);
        float lmax = fmaxf(fmaxf(v4[0], v4[1]), fmaxf(v4[2], v4[3]));
        // wave max (nonneg f32 bits order as u32)
        unsigned wm = (unsigned)__builtin_amdgcn_readlane(
            (int)dpp_red_umax(__float_as_uint(lmax)), 63);
        // smallest owning index among bitwise matches (balanced umin tree)
        unsigned c8[8], c4i[4];
#pragma unroll
        for (int j = 0; j < 8; j++) {
            unsigned a = (__float_as_uint(dist[2 * j]) == wm) ? idxr[2 * j] : 0xffffffffu;
            unsigned bq = (__float_as_uint(dist[2 * j + 1]) == wm) ? idxr[2 * j + 1] : 0xffffffffu;
            c8[j] = a < bq ? a : bq;
        }
#pragma unroll
        for (int j = 0; j < 4; j++) c4i[j] = c8[2 * j] < c8[2 * j + 1] ? c8[2 * j] : c8[2 * j + 1];
        unsigned c01 = c4i[0] < c4i[1] ? c4i[0] : c4i[1];
        unsigned c23 = c4i[2] < c4i[3] ? c4i[2] : c4i[3];
        unsigned mn = dpp_red_umin(c01 < c23 ? c01 : c23);
        int p = it & 1;
        if ((t & 63) == 63)
            sb[p][w] = ((unsigned long long)wm << 32) | (unsigned)~mn;
        __syncthreads();
        unsigned long long b0 = sb[p][0], b1 = sb[p][1], b2 = sb[p][2], b3 = sb[p][3];
        unsigned long long ma = b0 > b1 ? b0 : b1;
        unsigned long long mb = b2 > b3 ? b2 : b3;
        unsigned long long bw = ma > mb ? ma : mb;
        far = (int)(~(unsigned)(bw & 0xffffffffu)) & (N_ - 1);
        c4 = sp[far];
        // no trailing barrier: next iter writes the OTHER parity buffer; a wave
        // reaches iter+2's write only after all waves passed iter+1's barrier.
    }
    __syncthreads();
    for (int i = t; i < S_; i += 256) ct_idx[b * S_ + i] = sct[i];
}

// ---------------------------------------------------------------- kNN
// One block per (b,s). Order-preserving u32 keys precomputed once; per iter:
// u64 (key<<32)|idx min tree -> DPP u64 min -> 4-entry LDS combine (parity,
// single barrier). Tie -> smaller index (= lax.top_k selection set).
__global__ __launch_bounds__(256) void knn_kernel(const float* __restrict__ xyz,
                                                  const int* __restrict__ ct_idx,
                                                  int* __restrict__ gidx) {
    int bs = blockIdx.x;
    int b = bs >> 10;
    const float* xb = xyz + (size_t)b * 3 * N_;
    int ci = ct_idx[bs];
    float cx = xb[ci], cy = xb[N_ + ci], cz = xb[2 * N_ + ci];
    float cs = cx * cx + cy * cy + cz * cz;
    int t = threadIdx.x;
    unsigned long long pk[16];
#pragma unroll
    for (int j = 0; j < 16; j++) {
        int n = j * 256 + t;
        float x = xb[n], y = xb[N_ + n], z = xb[2 * N_ + n];
        float xn = x * x + y * y + z * z;
        float dot = cx * x + cy * y + cz * z;
        float val = cs + xn - 2.f * dot;        // reference formula order
        unsigned vb = __float_as_uint(val);
        unsigned key = (vb & 0x80000000u) ? ~vb : (vb | 0x80000000u);
        pk[j] = ((unsigned long long)key << 32) | (unsigned)n;
    }
    __shared__ unsigned long long sw[2][4];
    int out_base = bs * NS_;
    int w = t >> 6;
    for (int iter = 0; iter < NS_; iter++) {
        unsigned long long m8[8], m4[4];
#pragma unroll
        for (int j = 0; j < 8; j++) m8[j] = pk[2 * j] < pk[2 * j + 1] ? pk[2 * j] : pk[2 * j + 1];
#pragma unroll
        for (int j = 0; j < 4; j++) m4[j] = m8[2 * j] < m8[2 * j + 1] ? m8[2 * j] : m8[2 * j + 1];
        unsigned long long ma = m4[0] < m4[1] ? m4[0] : m4[1];
        unsigned long long mb = m4[2] < m4[3] ? m4[2] : m4[3];
        unsigned long long best = ma < mb ? ma : mb;
        unsigned hi = (unsigned)(best >> 32), lo = (unsigned)best;
        dpp_min_u64(hi, lo);
        int p = iter & 1;
        if ((t & 63) == 63) sw[p][w] = ((unsigned long long)hi << 32) | lo;
        __syncthreads();
        unsigned long long b0 = sw[p][0], b1 = sw[p][1], b2 = sw[p][2], b3 = sw[p][3];
        unsigned long long wa = b0 < b1 ? b0 : b1;
        unsigned long long wb = b2 < b3 ? b2 : b3;
        unsigned long long bw = wa < wb ? wa : wb;
        int n = (int)(unsigned)(bw & 0xffffffffu);
        if (t == 0) gidx[out_base + iter] = n;
        if ((n & 255) == t) pk[n >> 8] = 0xFFFFFFFF00000000ull | (unsigned)n;
        // parity double-buffer: no trailing barrier needed
    }
}

// ---------------------------------------------------------------- ct_p output
__global__ __launch_bounds__(256) void ctp_kernel(const float* __restrict__ xyz,
                                                  const int* __restrict__ ct_idx,
                                                  float* __restrict__ out) {
    int i = blockIdx.x * 256 + threadIdx.x;
    if (i >= B_ * 3 * S_) return;
    int b = i / (3 * S_);
    int rem = i - b * 3 * S_;
    int c = rem >> 10;
    int s = rem & (S_ - 1);
    int ci = ct_idx[b * S_ + s];
    out[i] = xyz[(size_t)b * 3 * N_ + (size_t)c * N_ + ci];
}

// ---------------------------------------------------------------- gather -> ft [33][R]
// ch 0-2: rel xyz; ch 3-31: points; ch 32: rd
__global__ __launch_bounds__(256) void gather_kernel(const float* __restrict__ xyz,
                                                     const float* __restrict__ pts,
                                                     const int* __restrict__ ct_idx,
                                                     const int* __restrict__ gidx,
                                                     float* __restrict__ ft) {
    int r = blockIdx.x * 256 + threadIdx.x;
    int b = r >> 15;
    int s = (r >> 5) & (S_ - 1);
    int g = gidx[r];
    int ci = ct_idx[b * S_ + s];
    const float* xb = xyz + (size_t)b * 3 * N_;
    float rx = xb[g] - xb[ci];
    float ry = xb[N_ + g] - xb[N_ + ci];
    float rz = xb[2 * N_ + g] - xb[2 * N_ + ci];
    ft[r] = rx;
    ft[(size_t)R_ + r] = ry;
    ft[(size_t)2 * R_ + r] = rz;
    float rd = sqrtf(fmaxf(rx * rx + ry * ry + rz * rz, 1e-12f));
    ft[(size_t)32 * R_ + r] = rd;
    const float* pb = pts + (size_t)b * 29 * N_;
#pragma unroll
    for (int c = 0; c < 29; c++) ft[(size_t)(3 + c) * R_ + r] = pb[(size_t)c * N_ + g];
}

// ---------------------------------------------------------------- conv1x1 (+optional input BN-affine+relu)
// 64 output channels per y-block; 2 rows per thread; weights broadcast from LDS.
// Fused BN-stats epilogue: per-block per-channel (sum, sumsq) via DPP wave sums
// -> partial[(c)*1024 + bx] (s) and [(c)*1024 + 512 + bx] (q). Deterministic.
template <int CIN, bool AFF>
__global__ __launch_bounds__(256) void convk(const float* __restrict__ xin,
                                             const float* __restrict__ W,
                                             const float* __restrict__ bias,
                                             const float* __restrict__ ab,
                                             float* __restrict__ out0,
                                             float* __restrict__ out1,
                                             float* __restrict__ partial) {
    __shared__ float Ws[CIN][64];
    __shared__ float bs_[64];
    __shared__ float as_[CIN], bbs[CIN];
    __shared__ float red[4][64][2];
    int oc0 = blockIdx.y * 64;
    for (int i = threadIdx.x; i < CIN * 64; i += 256) {
        int o = i & 63, c = i >> 6;
        Ws[c][o] = W[(size_t)(oc0 + o) * CIN + c];
    }
    if (threadIdx.x < 64) bs_[threadIdx.x] = bias[oc0 + threadIdx.x];
    if (AFF) {
        for (int i = threadIdx.x; i < CIN; i += 256) { as_[i] = ab[i]; bbs[i] = ab[CIN + i]; }
    }
    __syncthreads();
    size_t r0 = (size_t)blockIdx.x * 512 + threadIdx.x;
    float acc0[64], acc1[64];
#pragma unroll
    for (int o = 0; o < 64; o++) { acc0[o] = 0.f; acc1[o] = 0.f; }
    for (int c = 0; c < CIN; c++) {
        float x0 = xin[(size_t)c * R_ + r0];
        float x1 = xin[(size_t)c * R_ + r0 + 256];
        if (AFF) {
            float a = as_[c], bb = bbs[c];
            x0 = fmaxf(fmaf(a, x0, bb), 0.f);
            x1 = fmaxf(fmaf(a, x1, bb), 0.f);
        }
#pragma unroll
        for (int o = 0; o < 64; o++) {
            float w = Ws[c][o];
            acc0[o] = fmaf(x0, w, acc0[o]);
            acc1[o] = fmaf(x1, w, acc1[o]);
        }
    }
    float* outp = blockIdx.y ? out1 : out0;
    int wv = threadIdx.x >> 6;
#pragma unroll
    for (int o = 0; o < 64; o++) {
        float bv = bs_[o];
        float y0 = acc0[o] + bv;
        float y1 = acc1[o] + bv;
        outp[(size_t)o * R_ + r0] = y0;
        outp[(size_t)o * R_ + r0 + 256] = y1;
        float s = y0 + y1;
        float q = fmaf(y0, y0, y1 * y1);
        s = dpp_sum_f32(s);
        q = dpp_sum_f32(q);
        if ((threadIdx.x & 63) == 63) { red[wv][o][0] = s; red[wv][o][1] = q; }
    }
    __syncthreads();
    if (threadIdx.x < 64) {
        int o = threadIdx.x;
        float s = red[0][o][0] + red[1][o][0] + red[2][o][0] + red[3][o][0];
        float q = red[0][o][1] + red[1][o][1] + red[2][o][1] + red[3][o][1];
        partial[(size_t)(oc0 + o) * 1024 + blockIdx.x] = s;
        partial[(size_t)(oc0 + o) * 1024 + 512 + blockIdx.x] = q;
    }
}

// conv1 branch: 4 input channels = ft{0,1,2,32} (rel xyz + rd), fused stats
__global__ __launch_bounds__(256) void conv1_kernel(const float* __restrict__ ft,
                                                    const float* __restrict__ W,
                                                    const float* __restrict__ bias,
                                                    float* __restrict__ out,
                                                    float* __restrict__ partial) {
    __shared__ float Ws[4][64];
    __shared__ float bs_[64];
    __shared__ float red[4][64][2];
    {
        int i = threadIdx.x;
        if (i < 256) { int o = i & 63, c = i >> 6; Ws[c][o] = W[o * 4 + c]; }
    }
    if (threadIdx.x < 64) bs_[threadIdx.x] = bias[threadIdx.x];
    __syncthreads();
    size_t r0 = (size_t)blockIdx.x * 512 + threadIdx.x;
    float acc0[64], acc1[64];
#pragma unroll
    for (int o = 0; o < 64; o++) { acc0[o] = 0.f; acc1[o] = 0.f; }
    const int chs[4] = {0, 1, 2, 32};
#pragma unroll
    for (int c = 0; c < 4; c++) {
        int ch = chs[c];
        float x0 = ft[(size_t)ch * R_ + r0];
        float x1 = ft[(size_t)ch * R_ + r0 + 256];
#pragma unroll
        for (int o = 0; o < 64; o++) {
            float w = Ws[c][o];
            acc0[o] = fmaf(x0, w, acc0[o]);
            acc1[o] = fmaf(x1, w, acc1[o]);
        }
    }
    int wv = threadIdx.x >> 6;
#pragma unroll
    for (int o = 0; o < 64; o++) {
        float bv = bs_[o];
        float y0 = acc0[o] + bv;
        float y1 = acc1[o] + bv;
        out[(size_t)o * R_ + r0] = y0;
        out[(size_t)o * R_ + r0 + 256] = y1;
        float s = y0 + y1;
        float q = fmaf(y0, y0, y1 * y1);
        s = dpp_sum_f32(s);
        q = dpp_sum_f32(q);
        if ((threadIdx.x & 63) == 63) { red[wv][o][0] = s; red[wv][o][1] = q; }
    }
    __syncthreads();
    if (threadIdx.x < 64) {
        int o = threadIdx.x;
        float s = red[0][o][0] + red[1][o][0] + red[2][o][0] + red[3][o][0];
        float q = red[0][o][1] + red[1][o][1] + red[2][o][1] + red[3][o][1];
        partial[(size_t)o * 1024 + blockIdx.x] = s;
        partial[(size_t)o * 1024 + 512 + blockIdx.x] = q;
    }
}

// ---------------------------------------------------------------- BN finalize
// One wave per channel: reduce 512 block partials (s and q), emit affine (a,b).
__global__ __launch_bounds__(64) void statsf(const float* __restrict__ partial,
                                             const float* __restrict__ g,
                                             const float* __restrict__ be,
                                             float* __restrict__ ab, int C) {
    int c = blockIdx.x, t = threadIdx.x;
    float s = 0.f, q = 0.f;
    for (int i = t; i < 512; i += 64) {
        s += partial[(size_t)c * 1024 + i];
        q += partial[(size_t)c * 1024 + 512 + i];
    }
    s = dpp_sum_f32(s);
    q = dpp_sum_f32(q);
    if (t == 63) {
        float inv = 1.0f / (float)R_;
        float mean = s * inv;
        float var = q * inv - mean * mean;
        float a = g[c] / sqrtf(var + EPS_);
        ab[c] = a;
        ab[C + c] = be[c] - mean * a;
    }
}

// ---------------------------------------------------------------- epilogues
__global__ __launch_bounds__(128) void final_max(const float* __restrict__ yA,
                                                 const float* __restrict__ yC,
                                                 const float* __restrict__ ab,
                                                 float* __restrict__ out) {
    int bs = blockIdx.x;
    int c = threadIdx.x;
    const float* src = (c < 64 ? yA + (size_t)c * R_ : yC + (size_t)(c - 64) * R_) + (size_t)bs * NS_;
    float a = ab[c], bb = ab[128 + c];
    const float4* s4 = reinterpret_cast<const float4*>(src);
    float m = -FLT_MAX;
#pragma unroll
    for (int i = 0; i < 8; i++) {
        float4 v = s4[i];
        m = fmaxf(m, fmaxf(fmaf(a, v.x, bb), 0.f));
        m = fmaxf(m, fmaxf(fmaf(a, v.y, bb), 0.f));
        m = fmaxf(m, fmaxf(fmaf(a, v.z, bb), 0.f));
        m = fmaxf(m, fmaxf(fmaf(a, v.w, bb), 0.f));
    }
    int b = bs >> 10, s = bs & (S_ - 1);
    out[24576 + (size_t)b * 393216 + (size_t)c * 1024 + s] = m;
}

__global__ __launch_bounds__(128) void final_meanmax(const float* __restrict__ z1,
                                                     const float* __restrict__ z2,
                                                     const float* __restrict__ ab1,
                                                     const float* __restrict__ ab2,
                                                     float* __restrict__ out) {
    int bs = blockIdx.x;
    int c = threadIdx.x;
    const float* src;
    float a, bb;
    if (c < 64) { src = z1 + (size_t)c * R_; a = ab1[c]; bb = ab1[64 + c]; }
    else        { src = z2 + (size_t)(c - 64) * R_; a = ab2[c - 64]; bb = ab2[64 + (c - 64)]; }
    src += (size_t)bs * NS_;
    const float4* s4 = reinterpret_cast<const float4*>(src);
    float m = -FLT_MAX, sm = 0.f;
#pragma unroll
    for (int i = 0; i < 8; i++) {
        float4 v = s4[i];
        float t0 = fmaxf(fmaf(a, v.x, bb), 0.f); sm += t0; m = fmaxf(m, t0);
        float t1 = fmaxf(fmaf(a, v.y, bb), 0.f); sm += t1; m = fmaxf(m, t1);
        float t2 = fmaxf(fmaf(a, v.z, bb), 0.f); sm += t2; m = fmaxf(m, t2);
        float t3 = fmaxf(fmaf(a, v.w, bb), 0.f); sm += t3; m = fmaxf(m, t3);
    }
    int b = bs >> 10, s = bs & (S_ - 1);
    size_t ob = 24576 + (size_t)b * 393216;
    out[ob + (size_t)(128 + c) * 1024 + s] = sm * 0.03125f;
    out[ob + (size_t)(256 + c) * 1024 + s] = m;
}

// ================================================================ launch
extern "C" void kernel_launch(void* const* d_in, const int* in_sizes, int n_in,
                              void* d_out, int out_size, void* d_ws, size_t ws_size,
                              hipStream_t stream) {
    const float* xyz = (const float*)d_in[0];
    const float* pts = (const float*)d_in[1];
    const float* W0 = (const float*)d_in[2];  const float* b0 = (const float*)d_in[3];
    const float* g0 = (const float*)d_in[4];  const float* be0 = (const float*)d_in[5];
    const float* W1 = (const float*)d_in[6];  const float* b1 = (const float*)d_in[7];
    const float* g1 = (const float*)d_in[8];  const float* be1 = (const float*)d_in[9];
    const float* W2 = (const float*)d_in[10]; const float* b2 = (const float*)d_in[11];
    const float* g2 = (const float*)d_in[12]; const float* be2 = (const float*)d_in[13];
    const float* c1w = (const float*)d_in[14]; const float* c1b = (const float*)d_in[15];
    const float* bg1 = (const float*)d_in[16]; const float* bbe1 = (const float*)d_in[17];
    const float* c2w = (const float*)d_in[18]; const float* c2b = (const float*)d_in[19];
    const float* bg2 = (const float*)d_in[20]; const float* bbe2 = (const float*)d_in[21];
    float* out = (float*)d_out;

    // workspace layout (floats after the two int arrays)
    int* ct_idx = (int*)d_ws;                       // [8192]
    int* gidx = ct_idx + B_ * S_;                   // [262144]
    float* fbase = (float*)d_ws;
    float* ft = fbase + 270336;                     // 33*R
    float* A = ft + (size_t)33 * R_;                // 64*R   (y0 -> y2.lo -> z1)
    float* Bb = A + (size_t)64 * R_;                // 64*R   (y1 -> z2)
    float* C = Bb + (size_t)64 * R_;                // 64*R   (y2.hi)
    float* partial = C + (size_t)64 * R_;           // 128*1024
    float* ab0 = partial + 131072;                  // 128
    float* ab1 = ab0 + 128;                         // 128
    float* ab2 = ab1 + 128;                         // 256
    float* abz1 = ab2 + 256;                        // 128
    float* abz2 = abz1 + 128;                       // 128

    fps_kernel<<<B_, 256, 0, stream>>>(xyz, ct_idx);
    knn_kernel<<<B_ * S_, 256, 0, stream>>>(xyz, ct_idx, gidx);
    ctp_kernel<<<(B_ * 3 * S_ + 255) / 256, 256, 0, stream>>>(xyz, ct_idx, out);
    gather_kernel<<<R_ / 256, 256, 0, stream>>>(xyz, pts, ct_idx, gidx, ft);

    // MLP stack (stats fused into conv epilogues)
    convk<32, false><<<dim3(R_ / 512, 1), 256, 0, stream>>>(ft, W0, b0, nullptr, A, nullptr, partial);
    statsf<<<64, 64, 0, stream>>>(partial, g0, be0, ab0, 64);
    convk<64, true><<<dim3(R_ / 512, 1), 256, 0, stream>>>(A, W1, b1, ab0, Bb, nullptr, partial);
    statsf<<<64, 64, 0, stream>>>(partial, g1, be1, ab1, 64);
    convk<64, true><<<dim3(R_ / 512, 2), 256, 0, stream>>>(Bb, W2, b2, ab1, A, C, partial);
    statsf<<<128, 64, 0, stream>>>(partial, g2, be2, ab2, 128);
    final_max<<<B_ * S_, 128, 0, stream>>>(A, C, ab2, out);

    // conv2 branch (ft -> z2 in Bb)
    convk<32, false><<<dim3(R_ / 512, 1), 256, 0, stream>>>(ft, c2w, c2b, nullptr, Bb, nullptr, partial);
    statsf<<<64, 64, 0, stream>>>(partial, bg2, bbe2, abz2, 64);

    // conv1 branch (ft{0,1,2,32} -> z1 in A; A free after final_max)
    conv1_kernel<<<R_ / 512, 256, 0, stream>>>(ft, c1w, c1b, A, partial);
    statsf<<<64, 64, 0, stream>>>(partial, bg1, bbe1, abz1, 64);

    final_meanmax<<<B_ * S_, 128, 0, stream>>>(A, Bb, abz1, abz2, out);
}

// Round 8
// 1355.128 us; speedup vs baseline: 1.1504x; 1.0823x over previous
//
#include <hip/hip_runtime.h>
#include <cfloat>
#include <math.h>

constexpr int B_ = 8, N_ = 4096, S_ = 1024, NS_ = 32;
constexpr int R_ = B_ * S_ * NS_;          // 262144 rows (b,s,k)
constexpr float EPS_ = 1e-5f;

typedef float v2f __attribute__((ext_vector_type(2)));

// ---------------------------------------------------------------- DPP helpers
__device__ __forceinline__ unsigned dpp_red_umax(unsigned x) {
    unsigned t;
#define STEP_(ctrl) t = (unsigned)__builtin_amdgcn_update_dpp((int)x, (int)x, ctrl, 0xf, 0xf, false); x = x > t ? x : t;
    STEP_(0x111) STEP_(0x112) STEP_(0x114) STEP_(0x118) STEP_(0x142) STEP_(0x143)
#undef STEP_
    return x;
}
__device__ __forceinline__ unsigned dpp_red_umin(unsigned x) {
    unsigned t;
#define STEP_(ctrl) t = (unsigned)__builtin_amdgcn_update_dpp((int)x, (int)x, ctrl, 0xf, 0xf, false); x = x < t ? x : t;
    STEP_(0x111) STEP_(0x112) STEP_(0x114) STEP_(0x118) STEP_(0x142) STEP_(0x143)
#undef STEP_
    return x;
}
__device__ __forceinline__ void dpp_min_u64(unsigned& hi, unsigned& lo) {
#define STEP_(ctrl) { \
    unsigned h2 = (unsigned)__builtin_amdgcn_update_dpp((int)hi, (int)hi, ctrl, 0xf, 0xf, false); \
    unsigned l2 = (unsigned)__builtin_amdgcn_update_dpp((int)lo, (int)lo, ctrl, 0xf, 0xf, false); \
    if (h2 < hi || (h2 == hi && l2 < lo)) { hi = h2; lo = l2; } }
    STEP_(0x111) STEP_(0x112) STEP_(0x114) STEP_(0x118) STEP_(0x142) STEP_(0x143)
#undef STEP_
}
__device__ __forceinline__ float dpp_sum_f32(float x) {
#define ADD_(ctrl, rm) { \
    int t_ = __builtin_amdgcn_update_dpp(0, __float_as_int(x), ctrl, rm, 0xf, true); \
    x += __int_as_float(t_); }
    ADD_(0x111, 0xf) ADD_(0x112, 0xf) ADD_(0x114, 0xf) ADD_(0x118, 0xf)
    ADD_(0x142, 0xa) ADD_(0x143, 0xc)
#undef ADD_
    return x;
}

// ---------------------------------------------------------------- pts transpose
// ptsT[b][n][32]: cols 0-28 = points channels, 29-31 = xyz. Point-major rows
// make gather's per-neighbor reads 2 cache lines instead of 32.
__global__ __launch_bounds__(256) void transpose_kernel(const float* __restrict__ xyz,
                                                        const float* __restrict__ pts,
                                                        float* __restrict__ ptsT) {
    int idx = blockIdx.x * 256 + threadIdx.x;      // 32768 points total
    int b = idx >> 12, n = idx & (N_ - 1);
    float* row = ptsT + (size_t)idx * 32;
    const float* pb = pts + (size_t)b * 29 * N_;
#pragma unroll
    for (int c = 0; c < 29; c++) row[c] = pb[(size_t)c * N_ + n];
    const float* xb = xyz + (size_t)b * 3 * N_;
    row[29] = xb[n];
    row[30] = xb[N_ + n];
    row[31] = xb[2 * N_ + n];
}

// ---------------------------------------------------------------- FPS
// r3 structure verbatim (best measured: 692 us): 256 thr x 16 strided pts,
// sx/sy/sz LDS, in-loop t0 store, two-phase 32-bit DPP reduce, 4-entry u64
// LDS combine (parity double-buffer, single barrier). Only bit-exact tweaks:
// packed-f32 update (same IEEE ops per component) and reshaped exact trees.
__global__ __launch_bounds__(256) void fps_kernel(const float* __restrict__ xyz,
                                                  int* __restrict__ ct_idx) {
    int b = blockIdx.x;
    const float* xb = xyz + (size_t)b * 3 * N_;
    int t = threadIdx.x;
    __shared__ float sx[N_], sy[N_], sz[N_];
    __shared__ unsigned long long sb[2][4];
    for (int i = t; i < N_; i += 256) {
        sx[i] = xb[i];
        sy[i] = xb[N_ + i];
        sz[i] = xb[2 * N_ + i];
    }
    v2f px[8], py[8], pz[8], dist[8];
#pragma unroll
    for (int k = 0; k < 8; k++) {
        int n0 = (2 * k) * 256 + t, n1 = (2 * k + 1) * 256 + t;
        px[k] = (v2f){xb[n0], xb[n1]};
        py[k] = (v2f){xb[N_ + n0], xb[N_ + n1]};
        pz[k] = (v2f){xb[2 * N_ + n0], xb[2 * N_ + n1]};
        dist[k] = (v2f){1e10f, 1e10f};
    }
    __syncthreads();
    float cx = sx[0], cy = sy[0], cz = sz[0];
    int far = 0;
    int w = t >> 6;
    for (int it = 0; it < S_; it++) {
        if (t == 0) ct_idx[b * S_ + it] = far;
        v2f cx2 = (v2f){cx, cx}, cy2 = (v2f){cy, cy}, cz2 = (v2f){cz, cz};
#pragma unroll
        for (int k = 0; k < 8; k++) {
            v2f dx = px[k] - cx2, dy = py[k] - cy2, dz = pz[k] - cz2;
            v2f d = dx * dx;
            d = __builtin_elementwise_fma(dy, dy, d);
            d = __builtin_elementwise_fma(dz, dz, d);   // per-component same chain
            dist[k] = __builtin_elementwise_min(dist[k], d);
        }
        // exact max tree (max is associative-exact; any shape gives same bits)
        v2f m4[4];
#pragma unroll
        for (int k = 0; k < 4; k++)
            m4[k] = __builtin_elementwise_max(dist[2 * k], dist[2 * k + 1]);
        v2f m2a = __builtin_elementwise_max(m4[0], m4[1]);
        v2f m2b = __builtin_elementwise_max(m4[2], m4[3]);
        v2f m1 = __builtin_elementwise_max(m2a, m2b);
        float lmax = fmaxf(m1.x, m1.y);
        unsigned wm = (unsigned)__builtin_amdgcn_readlane(
            (int)dpp_red_umax(__float_as_uint(lmax)), 63);
        // smallest owning index among bitwise matches
        unsigned c8[8], c4i[4];
#pragma unroll
        for (int k = 0; k < 8; k++) {
            unsigned a = (__float_as_uint(dist[k].x) == wm)
                             ? (unsigned)((2 * k) * 256 + t) : 0xffffffffu;
            unsigned bq = (__float_as_uint(dist[k].y) == wm)
                             ? (unsigned)((2 * k + 1) * 256 + t) : 0xffffffffu;
            c8[k] = a < bq ? a : bq;
        }
#pragma unroll
        for (int k = 0; k < 4; k++) c4i[k] = c8[2 * k] < c8[2 * k + 1] ? c8[2 * k] : c8[2 * k + 1];
        unsigned c01 = c4i[0] < c4i[1] ? c4i[0] : c4i[1];
        unsigned c23 = c4i[2] < c4i[3] ? c4i[2] : c4i[3];
        unsigned mn = dpp_red_umin(c01 < c23 ? c01 : c23);
        int p = it & 1;
        if ((t & 63) == 63)
            sb[p][w] = ((unsigned long long)wm << 32) | (unsigned)~mn;
        __syncthreads();
        unsigned long long b0 = sb[p][0], b1 = sb[p][1], b2 = sb[p][2], b3 = sb[p][3];
        unsigned long long ma = b0 > b1 ? b0 : b1;
        unsigned long long mb = b2 > b3 ? b2 : b3;
        unsigned long long bw = ma > mb ? ma : mb;
        far = (int)(~(unsigned)(bw & 0xffffffffu)) & (N_ - 1);
        cx = sx[far]; cy = sy[far]; cz = sz[far];
    }
}

// ---------------------------------------------------------------- kNN (unchanged)
__global__ __launch_bounds__(256) void knn_kernel(const float* __restrict__ xyz,
                                                  const int* __restrict__ ct_idx,
                                                  int* __restrict__ gidx) {
    int bs = blockIdx.x;
    int b = bs >> 10;
    const float* xb = xyz + (size_t)b * 3 * N_;
    int ci = ct_idx[bs];
    float cx = xb[ci], cy = xb[N_ + ci], cz = xb[2 * N_ + ci];
    float cs = cx * cx + cy * cy + cz * cz;
    int t = threadIdx.x;
    unsigned long long pk[16];
#pragma unroll
    for (int j = 0; j < 16; j++) {
        int n = j * 256 + t;
        float x = xb[n], y = xb[N_ + n], z = xb[2 * N_ + n];
        float xn = x * x + y * y + z * z;
        float dot = cx * x + cy * y + cz * z;
        float val = cs + xn - 2.f * dot;        // reference formula order
        unsigned vb = __float_as_uint(val);
        unsigned key = (vb & 0x80000000u) ? ~vb : (vb | 0x80000000u);
        pk[j] = ((unsigned long long)key << 32) | (unsigned)n;
    }
    __shared__ unsigned long long sw[2][4];
    int out_base = bs * NS_;
    int w = t >> 6;
    for (int iter = 0; iter < NS_; iter++) {
        unsigned long long m8[8], m4[4];
#pragma unroll
        for (int j = 0; j < 8; j++) m8[j] = pk[2 * j] < pk[2 * j + 1] ? pk[2 * j] : pk[2 * j + 1];
#pragma unroll
        for (int j = 0; j < 4; j++) m4[j] = m8[2 * j] < m8[2 * j + 1] ? m8[2 * j] : m8[2 * j + 1];
        unsigned long long ma = m4[0] < m4[1] ? m4[0] : m4[1];
        unsigned long long mb = m4[2] < m4[3] ? m4[2] : m4[3];
        unsigned long long best = ma < mb ? ma : mb;
        unsigned hi = (unsigned)(best >> 32), lo = (unsigned)best;
        dpp_min_u64(hi, lo);
        int p = iter & 1;
        if ((t & 63) == 63) sw[p][w] = ((unsigned long long)hi << 32) | lo;
        __syncthreads();
        unsigned long long b0 = sw[p][0], b1 = sw[p][1], b2 = sw[p][2], b3 = sw[p][3];
        unsigned long long wa = b0 < b1 ? b0 : b1;
        unsigned long long wb = b2 < b3 ? b2 : b3;
        unsigned long long bw = wa < wb ? wa : wb;
        int n = (int)(unsigned)(bw & 0xffffffffu);
        if (t == 0) gidx[out_base + iter] = n;
        if ((n & 255) == t) pk[n >> 8] = 0xFFFFFFFF00000000ull | (unsigned)n;
    }
}

// ---------------------------------------------------------------- gather (+ctp fused)
// reads point-major ptsT rows (2 cache lines per neighbor); writes ft [33][R]
__global__ __launch_bounds__(256) void gather_kernel(const float* __restrict__ ptsT,
                                                     const float* __restrict__ xyz,
                                                     const int* __restrict__ ct_idx,
                                                     const int* __restrict__ gidx,
                                                     float* __restrict__ ft,
                                                     float* __restrict__ out) {
    int r = blockIdx.x * 256 + threadIdx.x;
    int b = r >> 15;
    int s = (r >> 5) & (S_ - 1);
    int g = gidx[r];
    int ci = ct_idx[b * S_ + s];
    const float4* rowg = (const float4*)(ptsT + ((size_t)(b << 12) + g) * 32);
    float4 v[8];
#pragma unroll
    for (int i = 0; i < 8; i++) v[i] = rowg[i];
    float4 cw = ((const float4*)(ptsT + ((size_t)(b << 12) + ci) * 32))[7]; // {c28,x,y,z}
    float rx = v[7].y - cw.y;
    float ry = v[7].z - cw.z;
    float rz = v[7].w - cw.w;
    ft[r] = rx;
    ft[(size_t)R_ + r] = ry;
    ft[(size_t)2 * R_ + r] = rz;
    float rd = sqrtf(fmaxf(rx * rx + ry * ry + rz * rz, 1e-12f));
    ft[(size_t)32 * R_ + r] = rd;
    const float vals[32] = {v[0].x, v[0].y, v[0].z, v[0].w, v[1].x, v[1].y, v[1].z, v[1].w,
                            v[2].x, v[2].y, v[2].z, v[2].w, v[3].x, v[3].y, v[3].z, v[3].w,
                            v[4].x, v[4].y, v[4].z, v[4].w, v[5].x, v[5].y, v[5].z, v[5].w,
                            v[6].x, v[6].y, v[6].z, v[6].w, v[7].x, 0.f, 0.f, 0.f};
#pragma unroll
    for (int c = 0; c < 29; c++) ft[(size_t)(3 + c) * R_ + r] = vals[c];
    // fused ct_p output (first 24576 threads)
    if (r < B_ * 3 * S_) {
        int bb = r / (3 * S_);
        int rem = r - bb * 3 * S_;
        int cc = rem >> 10;
        int ss = rem & (S_ - 1);
        int cidx = ct_idx[bb * S_ + ss];
        out[r] = xyz[(size_t)bb * 3 * N_ + (size_t)cc * N_ + cidx];
    }
}

// ---------------------------------------------------------------- conv1x1
// PRO: compute input BN affine from prev-layer partials in prologue (fused
// statsf), apply affine+relu on input. Double-buffered partials (pread/pwrite)
// avoid the prologue-read vs epilogue-write race.
template <int CIN, bool PRO>
__global__ __launch_bounds__(256) void convk(const float* __restrict__ xin,
                                             const float* __restrict__ W,
                                             const float* __restrict__ bias,
                                             const float* __restrict__ pread,
                                             const float* __restrict__ g,
                                             const float* __restrict__ be,
                                             float* __restrict__ pwrite, int pofs,
                                             float* __restrict__ out0,
                                             float* __restrict__ out1) {
    __shared__ float Ws[CIN][64];
    __shared__ float bs_[64];
    __shared__ float as_[CIN], bbs[CIN];
    __shared__ float red[4][64][2];
    int oc0 = blockIdx.y * 64;
    for (int i = threadIdx.x; i < CIN * 64; i += 256) {
        int o = i & 63, c = i >> 6;
        Ws[c][o] = W[(size_t)(oc0 + o) * CIN + c];
    }
    if (threadIdx.x < 64) bs_[threadIdx.x] = bias[oc0 + threadIdx.x];
    if (PRO) {
        int c = threadIdx.x >> 2, sub = threadIdx.x & 3;
        const float* ps = pread + (size_t)c * 1024 + sub * 128;
        float s = 0.f, q = 0.f;
        for (int i = 0; i < 128; i++) { s += ps[i]; q += ps[512 + i]; }
        s += __shfl_xor(s, 1); s += __shfl_xor(s, 2);
        q += __shfl_xor(q, 1); q += __shfl_xor(q, 2);
        if (sub == 0) {
            float inv = 1.0f / (float)R_;
            float mean = s * inv;
            float var = q * inv - mean * mean;
            float a = g[c] / sqrtf(var + EPS_);
            as_[c] = a;
            bbs[c] = be[c] - mean * a;
        }
    }
    __syncthreads();
    size_t r0 = (size_t)blockIdx.x * 512 + threadIdx.x;
    float acc0[64], acc1[64];
#pragma unroll
    for (int o = 0; o < 64; o++) { acc0[o] = 0.f; acc1[o] = 0.f; }
    for (int c = 0; c < CIN; c++) {
        float x0 = xin[(size_t)c * R_ + r0];
        float x1 = xin[(size_t)c * R_ + r0 + 256];
        if (PRO) {
            float a = as_[c], bb = bbs[c];
            x0 = fmaxf(fmaf(a, x0, bb), 0.f);
            x1 = fmaxf(fmaf(a, x1, bb), 0.f);
        }
#pragma unroll
        for (int o = 0; o < 64; o++) {
            float w = Ws[c][o];
            acc0[o] = fmaf(x0, w, acc0[o]);
            acc1[o] = fmaf(x1, w, acc1[o]);
        }
    }
    float* outp = blockIdx.y ? out1 : out0;
    int wv = threadIdx.x >> 6;
#pragma unroll
    for (int o = 0; o < 64; o++) {
        float bv = bs_[o];
        float y0 = acc0[o] + bv;
        float y1 = acc1[o] + bv;
        outp[(size_t)o * R_ + r0] = y0;
        outp[(size_t)o * R_ + r0 + 256] = y1;
        float s = y0 + y1;
        float q = fmaf(y0, y0, y1 * y1);
        s = dpp_sum_f32(s);
        q = dpp_sum_f32(q);
        if ((threadIdx.x & 63) == 63) { red[wv][o][0] = s; red[wv][o][1] = q; }
    }
    __syncthreads();
    if (threadIdx.x < 64) {
        int o = threadIdx.x;
        float s = red[0][o][0] + red[1][o][0] + red[2][o][0] + red[3][o][0];
        float q = red[0][o][1] + red[1][o][1] + red[2][o][1] + red[3][o][1];
        pwrite[(size_t)(pofs + oc0 + o) * 1024 + blockIdx.x] = s;
        pwrite[(size_t)(pofs + oc0 + o) * 1024 + 512 + blockIdx.x] = q;
    }
}

// conv1 branch: 4 input channels = ft{0,1,2,32}
__global__ __launch_bounds__(256) void conv1_kernel(const float* __restrict__ ft,
                                                    const float* __restrict__ W,
                                                    const float* __restrict__ bias,
                                                    float* __restrict__ out,
                                                    float* __restrict__ pwrite, int pofs) {
    __shared__ float Ws[4][64];
    __shared__ float bs_[64];
    __shared__ float red[4][64][2];
    {
        int i = threadIdx.x;
        if (i < 256) { int o = i & 63, c = i >> 6; Ws[c][o] = W[o * 4 + c]; }
    }
    if (threadIdx.x < 64) bs_[threadIdx.x] = bias[threadIdx.x];
    __syncthreads();
    size_t r0 = (size_t)blockIdx.x * 512 + threadIdx.x;
    float acc0[64], acc1[64];
#pragma unroll
    for (int o = 0; o < 64; o++) { acc0[o] = 0.f; acc1[o] = 0.f; }
    const int chs[4] = {0, 1, 2, 32};
#pragma unroll
    for (int c = 0; c < 4; c++) {
        int ch = chs[c];
        float x0 = ft[(size_t)ch * R_ + r0];
        float x1 = ft[(size_t)ch * R_ + r0 + 256];
#pragma unroll
        for (int o = 0; o < 64; o++) {
            float w = Ws[c][o];
            acc0[o] = fmaf(x0, w, acc0[o]);
            acc1[o] = fmaf(x1, w, acc1[o]);
        }
    }
    int wv = threadIdx.x >> 6;
#pragma unroll
    for (int o = 0; o < 64; o++) {
        float bv = bs_[o];
        float y0 = acc0[o] + bv;
        float y1 = acc1[o] + bv;
        out[(size_t)o * R_ + r0] = y0;
        out[(size_t)o * R_ + r0 + 256] = y1;
        float s = y0 + y1;
        float q = fmaf(y0, y0, y1 * y1);
        s = dpp_sum_f32(s);
        q = dpp_sum_f32(q);
        if ((threadIdx.x & 63) == 63) { red[wv][o][0] = s; red[wv][o][1] = q; }
    }
    __syncthreads();
    if (threadIdx.x < 64) {
        int o = threadIdx.x;
        float s = red[0][o][0] + red[1][o][0] + red[2][o][0] + red[3][o][0];
        float q = red[0][o][1] + red[1][o][1] + red[2][o][1] + red[3][o][1];
        pwrite[(size_t)(pofs + o) * 1024 + blockIdx.x] = s;
        pwrite[(size_t)(pofs + o) * 1024 + 512 + blockIdx.x] = q;
    }
}

// ---------------------------------------------------------------- BN finalize
__global__ __launch_bounds__(64) void statsf(const float* __restrict__ partial,
                                             const float* __restrict__ g,
                                             const float* __restrict__ be,
                                             float* __restrict__ ab, int C) {
    int c = blockIdx.x, t = threadIdx.x;
    float s = 0.f, q = 0.f;
    for (int i = t; i < 512; i += 64) {
        s += partial[(size_t)c * 1024 + i];
        q += partial[(size_t)c * 1024 + 512 + i];
    }
    s = dpp_sum_f32(s);
    q = dpp_sum_f32(q);
    if (t == 63) {
        float inv = 1.0f / (float)R_;
        float mean = s * inv;
        float var = q * inv - mean * mean;
        float a = g[c] / sqrtf(var + EPS_);
        ab[c] = a;
        ab[C + c] = be[c] - mean * a;
    }
}

// combined branch stats: channels 0-63 -> (g1,be1), 64-127 -> (g2,be2)
__global__ __launch_bounds__(64) void statsf2(const float* __restrict__ partial,
                                              const float* __restrict__ g1,
                                              const float* __restrict__ be1,
                                              const float* __restrict__ g2,
                                              const float* __restrict__ be2,
                                              float* __restrict__ ab) {
    int c = blockIdx.x, t = threadIdx.x;
    float s = 0.f, q = 0.f;
    for (int i = t; i < 512; i += 64) {
        s += partial[(size_t)c * 1024 + i];
        q += partial[(size_t)c * 1024 + 512 + i];
    }
    s = dpp_sum_f32(s);
    q = dpp_sum_f32(q);
    if (t == 63) {
        float gv = c < 64 ? g1[c] : g2[c - 64];
        float bv = c < 64 ? be1[c] : be2[c - 64];
        float inv = 1.0f / (float)R_;
        float mean = s * inv;
        float var = q * inv - mean * mean;
        float a = gv / sqrtf(var + EPS_);
        ab[c] = a;
        ab[128 + c] = bv - mean * a;
    }
}

// ---------------------------------------------------------------- epilogues
__global__ __launch_bounds__(128) void final_max(const float* __restrict__ yA,
                                                 const float* __restrict__ yC,
                                                 const float* __restrict__ ab,
                                                 float* __restrict__ out) {
    int bs = blockIdx.x;
    int c = threadIdx.x;
    const float* src = (c < 64 ? yA + (size_t)c * R_ : yC + (size_t)(c - 64) * R_) + (size_t)bs * NS_;
    float a = ab[c], bb = ab[128 + c];
    const float4* s4 = reinterpret_cast<const float4*>(src);
    float m = -FLT_MAX;
#pragma unroll
    for (int i = 0; i < 8; i++) {
        float4 v = s4[i];
        m = fmaxf(m, fmaxf(fmaf(a, v.x, bb), 0.f));
        m = fmaxf(m, fmaxf(fmaf(a, v.y, bb), 0.f));
        m = fmaxf(m, fmaxf(fmaf(a, v.z, bb), 0.f));
        m = fmaxf(m, fmaxf(fmaf(a, v.w, bb), 0.f));
    }
    int b = bs >> 10, s = bs & (S_ - 1);
    out[24576 + (size_t)b * 393216 + (size_t)c * 1024 + s] = m;
}

__global__ __launch_bounds__(128) void final_meanmax(const float* __restrict__ z1,
                                                     const float* __restrict__ z2,
                                                     const float* __restrict__ ab,
                                                     float* __restrict__ out) {
    int bs = blockIdx.x;
    int c = threadIdx.x;
    const float* src = (c < 64 ? z1 + (size_t)c * R_ : z2 + (size_t)(c - 64) * R_) + (size_t)bs * NS_;
    float a = ab[c], bb = ab[128 + c];
    const float4* s4 = reinterpret_cast<const float4*>(src);
    float m = -FLT_MAX, sm = 0.f;
#pragma unroll
    for (int i = 0; i < 8; i++) {
        float4 v = s4[i];
        float t0 = fmaxf(fmaf(a, v.x, bb), 0.f); sm += t0; m = fmaxf(m, t0);
        float t1 = fmaxf(fmaf(a, v.y, bb), 0.f); sm += t1; m = fmaxf(m, t1);
        float t2 = fmaxf(fmaf(a, v.z, bb), 0.f); sm += t2; m = fmaxf(m, t2);
        float t3 = fmaxf(fmaf(a, v.w, bb), 0.f); sm += t3; m = fmaxf(m, t3);
    }
    int b = bs >> 10, s = bs & (S_ - 1);
    size_t ob = 24576 + (size_t)b * 393216;
    out[ob + (size_t)(128 + c) * 1024 + s] = sm * 0.03125f;
    out[ob + (size_t)(256 + c) * 1024 + s] = m;
}

// ================================================================ launch
extern "C" void kernel_launch(void* const* d_in, const int* in_sizes, int n_in,
                              void* d_out, int out_size, void* d_ws, size_t ws_size,
                              hipStream_t stream) {
    const float* xyz = (const float*)d_in[0];
    const float* pts = (const float*)d_in[1];
    const float* W0 = (const float*)d_in[2];  const float* b0 = (const float*)d_in[3];
    const float* g0 = (const float*)d_in[4];  const float* be0 = (const float*)d_in[5];
    const float* W1 = (const float*)d_in[6];  const float* b1 = (const float*)d_in[7];
    const float* g1 = (const float*)d_in[8];  const float* be1 = (const float*)d_in[9];
    const float* W2 = (const float*)d_in[10]; const float* b2 = (const float*)d_in[11];
    const float* g2 = (const float*)d_in[12]; const float* be2 = (const float*)d_in[13];
    const float* c1w = (const float*)d_in[14]; const float* c1b = (const float*)d_in[15];
    const float* bg1 = (const float*)d_in[16]; const float* bbe1 = (const float*)d_in[17];
    const float* c2w = (const float*)d_in[18]; const float* c2b = (const float*)d_in[19];
    const float* bg2 = (const float*)d_in[20]; const float* bbe2 = (const float*)d_in[21];
    float* out = (float*)d_out;

    // workspace layout
    int* ct_idx = (int*)d_ws;                       // [8192]
    int* gidx = ct_idx + B_ * S_;                   // [262144]
    float* fbase = (float*)d_ws;
    float* ft = fbase + 270336;                     // 33*R
    float* A = ft + (size_t)33 * R_;                // 64*R  (ptsT alias -> y0 -> y2.lo -> z1)
    float* Bb = A + (size_t)64 * R_;                // 64*R  (y1 -> z2)
    float* C = Bb + (size_t)64 * R_;                // 64*R  (y2.hi)
    float* pbufA = C + (size_t)64 * R_;             // 128*1024
    float* pbufB = pbufA + 131072;                  // 128*1024
    float* ab2 = pbufB + 131072;                    // 256
    float* abz = ab2 + 256;                         // 256
    float* ptsT = A;                                // 1,048,576 floats, consumed before conv0 writes A

    transpose_kernel<<<B_ * N_ / 256, 256, 0, stream>>>(xyz, pts, ptsT);
    fps_kernel<<<B_, 256, 0, stream>>>(xyz, ct_idx);
    knn_kernel<<<B_ * S_, 256, 0, stream>>>(xyz, ct_idx, gidx);
    gather_kernel<<<R_ / 256, 256, 0, stream>>>(ptsT, xyz, ct_idx, gidx, ft, out);

    // MLP stack (ab0/ab1 fused into consumer prologues; partials double-buffered)
    convk<32, false><<<dim3(R_ / 512, 1), 256, 0, stream>>>(ft, W0, b0, nullptr, nullptr, nullptr, pbufA, 0, A, nullptr);
    convk<64, true><<<dim3(R_ / 512, 1), 256, 0, stream>>>(A, W1, b1, pbufA, g0, be0, pbufB, 0, Bb, nullptr);
    convk<64, true><<<dim3(R_ / 512, 2), 256, 0, stream>>>(Bb, W2, b2, pbufB, g1, be1, pbufA, 0, A, C);
    statsf<<<128, 64, 0, stream>>>(pbufA, g2, be2, ab2, 128);
    final_max<<<B_ * S_, 128, 0, stream>>>(A, C, ab2, out);

    // branch convs (ft -> z2 in Bb, z1 in A), combined stats, final
    convk<32, false><<<dim3(R_ / 512, 1), 256, 0, stream>>>(ft, c2w, c2b, nullptr, nullptr, nullptr, pbufB, 64, Bb, nullptr);
    conv1_kernel<<<R_ / 512, 256, 0, stream>>>(ft, c1w, c1b, A, pbufB, 0);
    statsf2<<<128, 64, 0, stream>>>(pbufB, bg1, bbe1, bg2, bbe2, abz);
    final_meanmax<<<B_ * S_, 128, 0, stream>>>(A, Bb, abz, out);
}